// Round 6
// baseline (1306.120 us; speedup 1.0000x reference)
//
#include <hip/hip_runtime.h>
#include <cstdint>
#include <cstddef>

#define N_TOK 8192
#define DIM   1024
#define NEXP  8
#define HID   4096
#define WELEM 4194304ull   // D*H elements per expert matrix

typedef __attribute__((ext_vector_type(8))) short short8v;
typedef __attribute__((ext_vector_type(4))) float f32x4;

__device__ __forceinline__ unsigned short f2bf(float f) {
  unsigned u = __builtin_bit_cast(unsigned, f);
  u += 0x7fffu + ((u >> 16) & 1u);     // RNE
  return (unsigned short)(u >> 16);
}

__device__ __forceinline__ void gload16(const void* g, void* l) {
  __builtin_amdgcn_global_load_lds(
      (const __attribute__((address_space(1))) void*)g,
      (__attribute__((address_space(3))) void*)l, 16, 0, 0);
}

// ---------------- x fp32 -> bf16 ----------------
__global__ void convert_x_k(const float* __restrict__ x, unsigned short* __restrict__ xb) {
  size_t i = ((size_t)blockIdx.x * 256 + threadIdx.x) * 8;
  float4 a = *(const float4*)(x + i);
  float4 b = *(const float4*)(x + i + 4);
  short8v v;
  v[0] = (short)f2bf(a.x); v[1] = (short)f2bf(a.y); v[2] = (short)f2bf(a.z); v[3] = (short)f2bf(a.w);
  v[4] = (short)f2bf(b.x); v[5] = (short)f2bf(b.y); v[6] = (short)f2bf(b.z); v[7] = (short)f2bf(b.w);
  *(short8v*)(xb + i) = v;
}

// ---------------- gate: fp32 logits, top-2, softmax (NO atomics) ----------------
__global__ void gate2_k(const float* __restrict__ x, const float* __restrict__ gw,
                        const float* __restrict__ gb, int* __restrict__ tassign,
                        float2* __restrict__ tprob) {
  int lane = threadIdx.x & 63, wid = threadIdx.x >> 6;
  int t = blockIdx.x * 4 + wid;
  const float* xr = x + (size_t)t * DIM;
  float acc[NEXP];
#pragma unroll
  for (int e = 0; e < NEXP; ++e) acc[e] = 0.f;
#pragma unroll
  for (int j = 0; j < DIM / 256; ++j) {
    int d0 = j * 256 + lane * 4;
    float4 xv = *(const float4*)(xr + d0);
    const float* gp = gw + (size_t)d0 * NEXP;
#pragma unroll
    for (int c = 0; c < 4; ++c) {
      float xs = (c == 0) ? xv.x : (c == 1) ? xv.y : (c == 2) ? xv.z : xv.w;
      float4 g0 = *(const float4*)(gp + c * NEXP);
      float4 g1 = *(const float4*)(gp + c * NEXP + 4);
      acc[0] += xs * g0.x; acc[1] += xs * g0.y; acc[2] += xs * g0.z; acc[3] += xs * g0.w;
      acc[4] += xs * g1.x; acc[5] += xs * g1.y; acc[6] += xs * g1.z; acc[7] += xs * g1.w;
    }
  }
#pragma unroll
  for (int e = 0; e < NEXP; ++e) {
    float v = acc[e];
#pragma unroll
    for (int s = 1; s < 64; s <<= 1) v += __shfl_xor(v, s);
    acc[e] = v;
  }
  if (lane == 0) {
    float lg[NEXP];
#pragma unroll
    for (int e = 0; e < NEXP; ++e) lg[e] = acc[e] + gb[e];
    int i0 = 0;
#pragma unroll
    for (int e = 1; e < NEXP; ++e) if (lg[e] > lg[i0]) i0 = e;
    int i1 = -1;
#pragma unroll
    for (int e = 0; e < NEXP; ++e) if (e != i0 && (i1 < 0 || lg[e] > lg[i1])) i1 = e;
    float ex = expf(lg[i1] - lg[i0]);       // <= 1
    float p0 = 1.f / (1.f + ex);
    float p1 = ex * p0;
    tassign[t] = i0 | (i1 << 8);
    tprob[t] = make_float2(p0, p1);
  }
}

// ---------------- routing: single block, LDS atomics only ----------------
__global__ void route_k(const int* __restrict__ tassign, const float2* __restrict__ tprob,
                        int* __restrict__ rtok, float* __restrict__ rwgt,
                        int* __restrict__ counts, int* __restrict__ ebase) {
  __shared__ int h[NEXP];
  __shared__ int cur[NEXP];
  int tid = threadIdx.x;
  if (tid < NEXP) h[tid] = 0;
  __syncthreads();
  for (int t = tid; t < N_TOK; t += 256) {
    int a = tassign[t];
    atomicAdd(&h[a & 255], 1);
    atomicAdd(&h[(a >> 8) & 255], 1);
  }
  __syncthreads();
  if (tid == 0) {
    int b = 0;
    for (int e = 0; e < NEXP; ++e) { counts[e] = h[e]; ebase[e] = b; cur[e] = b; b += h[e]; }
  }
  __syncthreads();
  for (int t = tid; t < N_TOK; t += 256) {
    int a = tassign[t];
    float2 p = tprob[t];
    int p0 = atomicAdd(&cur[a & 255], 1);
    rtok[p0] = t; rwgt[p0] = p.x;
    int p1 = atomicAdd(&cur[(a >> 8) & 255], 1);
    rtok[p1] = t; rwgt[p1] = p.y;
  }
}

// ---------------- aux loss ----------------
__global__ void aux_k(const int* __restrict__ counts, float* __restrict__ out) {
  if (threadIdx.x == 0) {
    float tot = 0.f, c[NEXP];
    for (int e = 0; e < NEXP; ++e) { c[e] = (float)counts[e]; tot += c[e]; }
    float a = 0.f;
    for (int e = 0; e < NEXP; ++e) { float d = c[e] / tot - 0.125f; a += d * d; }
    out[(size_t)N_TOK * DIM] = a;
  }
}

// ---------------- transpose + fp32->bf16; grid (4096 tiles, 3 mats, nexp) ----------------
__global__ void tcvt_k(const float* __restrict__ w1, const float* __restrict__ w2,
                       const float* __restrict__ wp, unsigned short* __restrict__ d1,
                       unsigned short* __restrict__ d2, unsigned short* __restrict__ d3) {
  int tile = blockIdx.x, mat = blockIdx.y;
  size_t eo = (size_t)blockIdx.z * WELEM;
  const float* src; unsigned short* dst; int R, C;
  if (mat == 0)      { src = w1 + eo; dst = d1 + eo; R = DIM; C = HID; }
  else if (mat == 1) { src = w2 + eo; dst = d2 + eo; R = DIM; C = HID; }
  else               { src = wp + eo; dst = d3 + eo; R = HID; C = DIM; }
  int tilesC = C >> 5;
  int tr = (tile / tilesC) << 5;
  int tc = (tile % tilesC) << 5;
  __shared__ float tl[32][33];
  int tx = threadIdx.x & 31, ty = threadIdx.x >> 5;
#pragma unroll
  for (int i = 0; i < 32; i += 8) tl[ty + i][tx] = src[(size_t)(tr + ty + i) * C + tc + tx];
  __syncthreads();
#pragma unroll
  for (int i = 0; i < 32; i += 8) dst[(size_t)(tc + ty + i) * R + tr + tx] = f2bf(tl[tx][ty + i]);
}

// ---------------- GEMM12: G = silu(Xe@W1+b1)*(Xe@W2+b2) ----------------
// BM=128 BN=128 BK=64; A direct-from-global with BOTH halves ping-pong-
// prefetched one full K-step ahead -> compute phase has ZERO vmcnt waits;
// B1,B2 double-buffered LDS via global_load_lds; one barrier drain per K-step.
__global__ __launch_bounds__(256) void gemm12_k(
    const unsigned short* __restrict__ xb,
    const unsigned short* __restrict__ w1b, const unsigned short* __restrict__ w2b,
    const float* __restrict__ b1, const float* __restrict__ b2,
    const int* __restrict__ rtok, const int* __restrict__ counts,
    const int* __restrict__ ebase, const int* __restrict__ gbase,
    unsigned short* __restrict__ G, int e0) {
  // XCD-chunked swizzle over the flattened grid (total divisible by 8)
  int f = blockIdx.x + gridDim.x * (blockIdx.y + gridDim.y * blockIdx.z);
  int total = gridDim.x * gridDim.y * gridDim.z;
  int cpx = total >> 3;
  int nf = (f & 7) * cpx + (f >> 3);
  int pe = gridDim.x * gridDim.y;
  int ez = nf / pe;
  int r  = nf - ez * pe;
  int nt = r >> 5;            // gridDim.x == 32
  int mt = r & 31;

  const int e = e0 + ez;
  const int ce = counts[e];
  if (mt * 128 >= ce) return;
  const int rb = ebase[e];
  const int gb_ = gbase[e];
  const unsigned short* w1t = w1b + (size_t)ez * WELEM;
  const unsigned short* w2t = w2b + (size_t)ez * WELEM;
  const float* b1e = b1 + (size_t)e * HID;
  const float* b2e = b2 + (size_t)e * HID;

  __shared__ __attribute__((aligned(16))) unsigned short sB1[2][128 * 64];
  __shared__ __attribute__((aligned(16))) unsigned short sB2[2][128 * 64];

  const int tid = threadIdx.x;
  const int lane = tid & 63;
  const int wid = tid >> 6;
  const int wm = wid >> 1, wn = wid & 1;

  // B staging: single base pointer + constant i*32*DIM offsets (VGPR diet)
  const int srow = tid >> 3;
  const int lcol = (((tid & 7) ^ (srow & 7)) << 3);
  const unsigned short* bs1 = w1t + (size_t)(nt * 128 + srow) * DIM + lcol;
  const unsigned short* bs2 = w2t + (size_t)(nt * 128 + srow) * DIM + lcol;
  const unsigned ldsb = (unsigned)(wid * 1024);  // wave-uniform; HW adds lane*16

  // A row pointers (token gather), 16B chunk per lane-quadrant
  const unsigned short* pA[4];
#pragma unroll
  for (int m = 0; m < 4; ++m) {
    int slot = mt * 128 + wm * 64 + m * 16 + (lane & 15);
    if (slot >= ce) slot = ce - 1;
    pA[m] = xb + (size_t)rtok[rb + slot] * DIM + ((lane >> 4) << 3);
  }

  f32x4 acc1[4][4] = {};
  f32x4 acc2[4][4] = {};
  short8v aL0[4], aH0[4], aL1[4], aH1[4];

#define STAGE12(BUF, K0)                                            \
  {                                                                 \
    _Pragma("unroll")                                               \
    for (int i = 0; i < 4; ++i) {                                   \
      gload16(bs1 + (K0) + i * 32 * DIM, (char*)sB1[BUF] + ldsb + i * 4096); \
      gload16(bs2 + (K0) + i * 32 * DIM, (char*)sB2[BUF] + ldsb + i * 4096); \
    }                                                               \
  }

#define LOADA(LO, HI, K0)                                           \
  {                                                                 \
    _Pragma("unroll")                                               \
    for (int m = 0; m < 4; ++m) {                                   \
      LO[m] = *(const short8v*)(pA[m] + (K0));                      \
      HI[m] = *(const short8v*)(pA[m] + (K0) + 32);                 \
    }                                                               \
  }

#define COMPUTE12(BUF, LO, HI)                                      \
  {                                                                 \
    _Pragma("unroll")                                               \
    for (int s = 0; s < 2; ++s) {                                   \
      short8v bf1[4], bf2[4];                                       \
      _Pragma("unroll")                                             \
      for (int n = 0; n < 4; ++n) {                                 \
        int row = wn * 64 + n * 16 + (lane & 15);                   \
        int p = (s * 4 + (lane >> 4)) ^ (row & 7);                  \
        bf1[n] = *(const short8v*)((const char*)sB1[BUF] + row * 128 + p * 16); \
        bf2[n] = *(const short8v*)((const char*)sB2[BUF] + row * 128 + p * 16); \
      }                                                             \
      _Pragma("unroll")                                             \
      for (int m = 0; m < 4; ++m)                                   \
        _Pragma("unroll")                                           \
        for (int n = 0; n < 4; ++n) {                               \
          acc1[m][n] = __builtin_amdgcn_mfma_f32_16x16x32_bf16(     \
              s ? HI[m] : LO[m], bf1[n], acc1[m][n], 0, 0, 0);      \
          acc2[m][n] = __builtin_amdgcn_mfma_f32_16x16x32_bf16(     \
              s ? HI[m] : LO[m], bf2[n], acc2[m][n], 0, 0, 0);      \
        }                                                           \
    }                                                               \
  }

  LOADA(aL0, aH0, 0);
  STAGE12(0, 0);
  __syncthreads();
  for (int i = 0; i < 7; ++i) {
    const int k2 = i * 128;          // element offset of even K-step
    STAGE12(1, k2 + 64);
    LOADA(aL1, aH1, k2 + 64);        // full next-step A prefetch
    __builtin_amdgcn_sched_barrier(0);
    COMPUTE12(0, aL0, aH0);          // zero vmcnt waits
    __syncthreads();
    STAGE12(0, k2 + 128);
    LOADA(aL0, aH0, k2 + 128);
    __builtin_amdgcn_sched_barrier(0);
    COMPUTE12(1, aL1, aH1);
    __syncthreads();
  }
  // kt = 14 (offset 896), buf0, set0; stage/prefetch kt=15
  STAGE12(1, 960);
  LOADA(aL1, aH1, 960);
  __builtin_amdgcn_sched_barrier(0);
  COMPUTE12(0, aL0, aH0);
  __syncthreads();
  // kt = 15, buf1, set1
  COMPUTE12(1, aL1, aH1);
#undef STAGE12
#undef LOADA
#undef COMPUTE12

#pragma unroll
  for (int n = 0; n < 4; ++n) {
    int col = nt * 128 + wn * 64 + n * 16 + (lane & 15);
    float bb1 = b1e[col], bb2 = b2e[col];
#pragma unroll
    for (int m = 0; m < 4; ++m) {
      int rbase = mt * 128 + wm * 64 + m * 16 + ((lane >> 4) << 2);
#pragma unroll
      for (int r2 = 0; r2 < 4; ++r2) {
        int slot = rbase + r2;
        if (slot < ce) {
          float h1 = acc1[m][n][r2] + bb1;
          float h2 = acc2[m][n][r2] + bb2;
          float sg = 1.0f / (1.0f + __expf(-h1));
          G[(size_t)(gb_ + slot) * HID + col] = f2bf(h1 * sg * h2);
        }
      }
    }
  }
}

// ---------------- GEMM3: out[token] += w*(G@Wp + bp) ----------------
// BM=128 BN=128 BK=64; A(G) + B(wpt) double-buffered LDS; 2-phase pipeline
__global__ __launch_bounds__(256) void gemm3_k(
    const unsigned short* __restrict__ G, const unsigned short* __restrict__ wpb,
    const float* __restrict__ bp, const int* __restrict__ rtok,
    const float* __restrict__ rwgt, const int* __restrict__ counts,
    const int* __restrict__ ebase, const int* __restrict__ gbase,
    float* __restrict__ out, int e0) {
  int f = blockIdx.x + gridDim.x * (blockIdx.y + gridDim.y * blockIdx.z);
  int total = gridDim.x * gridDim.y * gridDim.z;
  int cpx = total >> 3;
  int nf = (f & 7) * cpx + (f >> 3);
  int pe = gridDim.x * gridDim.y;
  int ez = nf / pe;
  int r  = nf - ez * pe;
  int nt = r >> 5;            // gridDim.x == 32
  int mt = r & 31;

  const int e = e0 + ez;
  const int ce = counts[e];
  if (mt * 128 >= ce) return;
  const int rb = ebase[e];
  const int gb_ = gbase[e];
  const unsigned short* wpt = wpb + (size_t)ez * WELEM;
  const float* bpe = bp + (size_t)e * DIM;

  __shared__ __attribute__((aligned(16))) unsigned short sA[2][128 * 64];
  __shared__ __attribute__((aligned(16))) unsigned short sB[2][128 * 64];

  const int tid = threadIdx.x;
  const int lane = tid & 63;
  const int wid = tid >> 6;
  const int wm = wid >> 1, wn = wid & 1;

  const unsigned short* asrc[4];
  const unsigned short* bsrc[4];
  unsigned ldso[4];
#pragma unroll
  for (int i = 0; i < 4; ++i) {
    int g = i * 256 + tid;
    int row = g >> 3, sl = g & 7;
    int lcol = ((sl ^ (row & 7)) << 3);
    asrc[i] = G + (size_t)(gb_ + mt * 128 + row) * HID + lcol;
    bsrc[i] = wpt + (size_t)(nt * 128 + row) * HID + lcol;
    ldso[i] = (unsigned)(i * 256 + wid * 64) * 16;
  }

  f32x4 acc[4][4] = {};

#define STAGE3(BUF, K0)                                             \
  {                                                                 \
    _Pragma("unroll")                                               \
    for (int i = 0; i < 4; ++i) {                                   \
      gload16(asrc[i] + (K0), (char*)sA[BUF] + ldso[i]);            \
      gload16(bsrc[i] + (K0), (char*)sB[BUF] + ldso[i]);            \
    }                                                               \
  }

#define COMPUTE3(BUF)                                               \
  {                                                                 \
    _Pragma("unroll")                                               \
    for (int s = 0; s < 2; ++s) {                                   \
      short8v af[4], bf[4];                                         \
      _Pragma("unroll")                                             \
      for (int m = 0; m < 4; ++m) {                                 \
        int row = wm * 64 + m * 16 + (lane & 15);                   \
        int p = (s * 4 + (lane >> 4)) ^ (row & 7);                  \
        af[m] = *(const short8v*)((const char*)sA[BUF] + row * 128 + p * 16); \
      }                                                             \
      _Pragma("unroll")                                             \
      for (int n = 0; n < 4; ++n) {                                 \
        int row = wn * 64 + n * 16 + (lane & 15);                   \
        int p = (s * 4 + (lane >> 4)) ^ (row & 7);                  \
        bf[n] = *(const short8v*)((const char*)sB[BUF] + row * 128 + p * 16); \
      }                                                             \
      _Pragma("unroll")                                             \
      for (int m = 0; m < 4; ++m)                                   \
        _Pragma("unroll")                                           \
        for (int n = 0; n < 4; ++n)                                 \
          acc[m][n] = __builtin_amdgcn_mfma_f32_16x16x32_bf16(af[m], bf[n], acc[m][n], 0, 0, 0); \
    }                                                               \
  }

  STAGE3(0, 0);
  __syncthreads();
  for (int kt = 0; kt < 63; ++kt) {
    STAGE3((kt + 1) & 1, (kt + 1) * 64);
    __builtin_amdgcn_sched_barrier(0);
    COMPUTE3(kt & 1);
    __syncthreads();
  }
  COMPUTE3(1);
#undef STAGE3
#undef COMPUTE3

  int colb = nt * 128 + wn * 64 + (lane & 15);
  float bpv[4];
#pragma unroll
  for (int n = 0; n < 4; ++n) bpv[n] = bpe[colb + n * 16];
#pragma unroll
  for (int m = 0; m < 4; ++m) {
    int rbase = mt * 128 + wm * 64 + m * 16 + ((lane >> 4) << 2);
#pragma unroll
    for (int r2 = 0; r2 < 4; ++r2) {
      int slot = rbase + r2;
      if (slot < ce) {
        int tok = rtok[rb + slot];
        float w = rwgt[rb + slot];
        float* ob = out + (size_t)tok * DIM + colb;
#pragma unroll
        for (int n = 0; n < 4; ++n)
          atomicAdd(ob + n * 16, w * (acc[m][n][r2] + bpv[n]));
      }
    }
  }
}

// ---------------- host ----------------
extern "C" void kernel_launch(void* const* d_in, const int* in_sizes, int n_in,
                              void* d_out, int out_size, void* d_ws, size_t ws_size,
                              hipStream_t stream) {
  const float* x  = (const float*)d_in[0];
  const float* gw = (const float*)d_in[1];
  const float* gb = (const float*)d_in[2];
  const float* w1 = (const float*)d_in[3];
  const float* b1 = (const float*)d_in[4];
  const float* w2 = (const float*)d_in[5];
  const float* b2 = (const float*)d_in[6];
  const float* wp = (const float*)d_in[7];
  const float* bp = (const float*)d_in[8];
  float* out = (float*)d_out;

  char* ws = (char*)d_ws;
  const size_t BIG_NEED = 352551008ull;
  bool big = ws_size >= BIG_NEED;

  unsigned short* xb = (unsigned short*)ws;                       // 16 MB
  unsigned short *Gp, *w1a, *w2a, *wpa;
  int* tassign; float2* tprob; int* rtok; float* rwgt; int* meta;
  if (big) {
    Gp  = (unsigned short*)(ws + 16777216);      // 134.2 MB (16384 global slots)
    w1a = (unsigned short*)(ws + 150994944);     // 64 MB
    w2a = (unsigned short*)(ws + 218103808);     // 64 MB
    wpa = (unsigned short*)(ws + 285212672);     // 64 MB
    tassign = (int*)(ws + 352321536);
    tprob   = (float2*)(ws + 352354304);
    rtok    = (int*)(ws + 352419840);
    rwgt    = (float*)(ws + 352485376);
    meta    = (int*)(ws + 352550912);            // counts[8], ebase[8], zbase[8]
  } else {
    Gp  = (unsigned short*)(ws + 16777216);      // 64 MB (local slots)
    w1a = (unsigned short*)(ws + 83886080);      // 8 MB per-expert
    w2a = (unsigned short*)(ws + 92274688);
    wpa = (unsigned short*)(ws + 100663296);
    tassign = (int*)(ws + 109051904);
    tprob   = (float2*)(ws + 109084672);
    rtok    = (int*)(ws + 109150208);
    rwgt    = (float*)(ws + 109215744);
    meta    = (int*)(ws + 109281280);
  }
  int* counts = meta;
  int* ebase  = meta + 8;
  int* zbase  = meta + 16;

  hipMemsetAsync(meta, 0, 96, stream);
  hipMemsetAsync(out, 0, (size_t)(N_TOK * DIM + 1) * sizeof(float), stream);

  convert_x_k<<<4096, 256, 0, stream>>>(x, xb);
  gate2_k<<<N_TOK / 4, 256, 0, stream>>>(x, gw, gb, tassign, tprob);
  route_k<<<1, 256, 0, stream>>>(tassign, tprob, rtok, rwgt, counts, ebase);
  aux_k<<<1, 64, 0, stream>>>(counts, out);

  if (big) {
    tcvt_k<<<dim3(4096, 3, NEXP), 256, 0, stream>>>(w1, w2, wp, w1a, w2a, wpa);
    gemm12_k<<<dim3(32, 32, NEXP), 256, 0, stream>>>(
        xb, w1a, w2a, b1, b2, rtok, counts, ebase, ebase, Gp, 0);
    gemm3_k<<<dim3(32, 8, NEXP), 256, 0, stream>>>(
        Gp, wpa, bp, rtok, rwgt, counts, ebase, ebase, out, 0);
  } else {
    for (int e = 0; e < NEXP; ++e) {
      tcvt_k<<<dim3(4096, 3, 1), 256, 0, stream>>>(
          w1 + (size_t)e * WELEM, w2 + (size_t)e * WELEM, wp + (size_t)e * WELEM,
          w1a, w2a, wpa);
      gemm12_k<<<dim3(32, 32, 1), 256, 0, stream>>>(
          xb, w1a, w2a, b1, b2, rtok, counts, ebase, zbase, Gp, e);
      gemm3_k<<<dim3(32, 8, 1), 256, 0, stream>>>(
          Gp, wpa, bp, rtok, rwgt, counts, ebase, zbase, out, e);
    }
  }
}

// Round 7
// 1302.857 us; speedup vs baseline: 1.0025x; 1.0025x over previous
//
#include <hip/hip_runtime.h>
#include <cstdint>
#include <cstddef>

#define N_TOK 8192
#define DIM   1024
#define NEXP  8
#define HID   4096
#define WELEM 4194304ull   // D*H elements per expert matrix

typedef __attribute__((ext_vector_type(8))) short short8v;
typedef __attribute__((ext_vector_type(4))) float f32x4;

__device__ __forceinline__ unsigned short f2bf(float f) {
  unsigned u = __builtin_bit_cast(unsigned, f);
  u += 0x7fffu + ((u >> 16) & 1u);     // RNE
  return (unsigned short)(u >> 16);
}
__device__ __forceinline__ float bf2f(unsigned short u) {
  return __builtin_bit_cast(float, (unsigned)u << 16);
}

__device__ __forceinline__ void gload16(const void* g, void* l) {
  __builtin_amdgcn_global_load_lds(
      (const __attribute__((address_space(1))) void*)g,
      (__attribute__((address_space(3))) void*)l, 16, 0, 0);
}

// ---------------- x fp32 -> bf16 ----------------
__global__ void convert_x_k(const float* __restrict__ x, unsigned short* __restrict__ xb) {
  size_t i = ((size_t)blockIdx.x * 256 + threadIdx.x) * 8;
  float4 a = *(const float4*)(x + i);
  float4 b = *(const float4*)(x + i + 4);
  short8v v;
  v[0] = (short)f2bf(a.x); v[1] = (short)f2bf(a.y); v[2] = (short)f2bf(a.z); v[3] = (short)f2bf(a.w);
  v[4] = (short)f2bf(b.x); v[5] = (short)f2bf(b.y); v[6] = (short)f2bf(b.z); v[7] = (short)f2bf(b.w);
  *(short8v*)(xb + i) = v;
}

// ---------------- gate: fp32 logits, top-2, softmax (NO atomics) ----------------
__global__ void gate2_k(const float* __restrict__ x, const float* __restrict__ gw,
                        const float* __restrict__ gb, int* __restrict__ tassign,
                        float2* __restrict__ tprob) {
  int lane = threadIdx.x & 63, wid = threadIdx.x >> 6;
  int t = blockIdx.x * 4 + wid;
  const float* xr = x + (size_t)t * DIM;
  float acc[NEXP];
#pragma unroll
  for (int e = 0; e < NEXP; ++e) acc[e] = 0.f;
#pragma unroll
  for (int j = 0; j < DIM / 256; ++j) {
    int d0 = j * 256 + lane * 4;
    float4 xv = *(const float4*)(xr + d0);
    const float* gp = gw + (size_t)d0 * NEXP;
#pragma unroll
    for (int c = 0; c < 4; ++c) {
      float xs = (c == 0) ? xv.x : (c == 1) ? xv.y : (c == 2) ? xv.z : xv.w;
      float4 g0 = *(const float4*)(gp + c * NEXP);
      float4 g1 = *(const float4*)(gp + c * NEXP + 4);
      acc[0] += xs * g0.x; acc[1] += xs * g0.y; acc[2] += xs * g0.z; acc[3] += xs * g0.w;
      acc[4] += xs * g1.x; acc[5] += xs * g1.y; acc[6] += xs * g1.z; acc[7] += xs * g1.w;
    }
  }
#pragma unroll
  for (int e = 0; e < NEXP; ++e) {
    float v = acc[e];
#pragma unroll
    for (int s = 1; s < 64; s <<= 1) v += __shfl_xor(v, s);
    acc[e] = v;
  }
  if (lane == 0) {
    float lg[NEXP];
#pragma unroll
    for (int e = 0; e < NEXP; ++e) lg[e] = acc[e] + gb[e];
    int i0 = 0;
#pragma unroll
    for (int e = 1; e < NEXP; ++e) if (lg[e] > lg[i0]) i0 = e;
    int i1 = -1;
#pragma unroll
    for (int e = 0; e < NEXP; ++e) if (e != i0 && (i1 < 0 || lg[e] > lg[i1])) i1 = e;
    float ex = expf(lg[i1] - lg[i0]);       // <= 1
    float p0 = 1.f / (1.f + ex);
    float p1 = ex * p0;
    tassign[t] = i0 | (i1 << 8);
    tprob[t] = make_float2(p0, p1);
  }
}

// ---------------- routing: single block, LDS atomics only ----------------
__global__ void route_k(const int* __restrict__ tassign, const float2* __restrict__ tprob,
                        int* __restrict__ rtok, float* __restrict__ rwgt,
                        int* __restrict__ counts, int* __restrict__ ebase) {
  __shared__ int h[NEXP];
  __shared__ int cur[NEXP];
  int tid = threadIdx.x;
  if (tid < NEXP) h[tid] = 0;
  __syncthreads();
  for (int t = tid; t < N_TOK; t += 256) {
    int a = tassign[t];
    atomicAdd(&h[a & 255], 1);
    atomicAdd(&h[(a >> 8) & 255], 1);
  }
  __syncthreads();
  if (tid == 0) {
    int b = 0;
    for (int e = 0; e < NEXP; ++e) { counts[e] = h[e]; ebase[e] = b; cur[e] = b; b += h[e]; }
  }
  __syncthreads();
  for (int t = tid; t < N_TOK; t += 256) {
    int a = tassign[t];
    float2 p = tprob[t];
    int p0 = atomicAdd(&cur[a & 255], 1);
    rtok[p0] = t; rwgt[p0] = p.x;
    int p1 = atomicAdd(&cur[(a >> 8) & 255], 1);
    rtok[p1] = t; rwgt[p1] = p.y;
  }
}

// ---------------- aux loss ----------------
__global__ void aux_k(const int* __restrict__ counts, float* __restrict__ out) {
  if (threadIdx.x == 0) {
    float tot = 0.f, c[NEXP];
    for (int e = 0; e < NEXP; ++e) { c[e] = (float)counts[e]; tot += c[e]; }
    float a = 0.f;
    for (int e = 0; e < NEXP; ++e) { float d = c[e] / tot - 0.125f; a += d * d; }
    out[(size_t)N_TOK * DIM] = a;
  }
}

// ---------------- transpose + fp32->bf16; grid (4096 tiles, 3 mats, nexp) ----------------
__global__ void tcvt_k(const float* __restrict__ w1, const float* __restrict__ w2,
                       const float* __restrict__ wp, unsigned short* __restrict__ d1,
                       unsigned short* __restrict__ d2, unsigned short* __restrict__ d3) {
  int tile = blockIdx.x, mat = blockIdx.y;
  size_t eo = (size_t)blockIdx.z * WELEM;
  const float* src; unsigned short* dst; int R, C;
  if (mat == 0)      { src = w1 + eo; dst = d1 + eo; R = DIM; C = HID; }
  else if (mat == 1) { src = w2 + eo; dst = d2 + eo; R = DIM; C = HID; }
  else               { src = wp + eo; dst = d3 + eo; R = HID; C = DIM; }
  int tilesC = C >> 5;
  int tr = (tile / tilesC) << 5;
  int tc = (tile % tilesC) << 5;
  __shared__ float tl[32][33];
  int tx = threadIdx.x & 31, ty = threadIdx.x >> 5;
#pragma unroll
  for (int i = 0; i < 32; i += 8) tl[ty + i][tx] = src[(size_t)(tr + ty + i) * C + tc + tx];
  __syncthreads();
#pragma unroll
  for (int i = 0; i < 32; i += 8) dst[(size_t)(tc + ty + i) * R + tr + tx] = f2bf(tl[tx][ty + i]);
}

// ================= 256x256 2-phase GEMM core =================
// 512 threads, 8 waves (2M x 4N), wave tile 128x64, BK=64,
// sA/sB double-buffered 128KB LDS, XOR-swizzled both sides.
#define STG(SD, BUFI, P0, P1, P2, P3, K0)                           \
  gload16(P0 + (K0), (char*)SD[BUFI] + stg);                        \
  gload16(P1 + (K0), (char*)SD[BUFI] + stg + 8192);                 \
  gload16(P2 + (K0), (char*)SD[BUFI] + stg + 16384);                \
  gload16(P3 + (K0), (char*)SD[BUFI] + stg + 24576);

#define CMP(BUFI)                                                   \
  {                                                                 \
    _Pragma("unroll")                                               \
    for (int s = 0; s < 2; ++s) {                                   \
      short8v af[8], bf[4];                                         \
      _Pragma("unroll")                                             \
      for (int m = 0; m < 8; ++m) {                                 \
        int row = wm * 128 + m * 16 + (lane & 15);                  \
        int p = (s * 4 + (lane >> 4)) ^ (row & 7);                  \
        af[m] = *(const short8v*)((const char*)sA[BUFI] + row * 128 + p * 16); \
      }                                                             \
      _Pragma("unroll")                                             \
      for (int n = 0; n < 4; ++n) {                                 \
        int row = wn * 64 + n * 16 + (lane & 15);                   \
        int p = (s * 4 + (lane >> 4)) ^ (row & 7);                  \
        bf[n] = *(const short8v*)((const char*)sB[BUFI] + row * 128 + p * 16); \
      }                                                             \
      _Pragma("unroll")                                             \
      for (int m = 0; m < 8; ++m)                                   \
        _Pragma("unroll")                                           \
        for (int n = 0; n < 4; ++n)                                 \
          acc[m][n] = __builtin_amdgcn_mfma_f32_16x16x32_bf16(af[m], bf[n], acc[m][n], 0, 0, 0); \
    }                                                               \
  }

#define GEMM_LOOP(NTILE)                                            \
  STG(sA, 0, pa0, pa1, pa2, pa3, 0);                                \
  STG(sB, 0, pb0, pb1, pb2, pb3, 0);                                \
  __syncthreads();                                                  \
  _Pragma("unroll 1")                                               \
  for (int t = 0; t < (NTILE) / 2 - 1; ++t) {                       \
    STG(sA, 1, pa0, pa1, pa2, pa3, (2 * t + 1) * 64);               \
    STG(sB, 1, pb0, pb1, pb2, pb3, (2 * t + 1) * 64);               \
    __builtin_amdgcn_sched_barrier(0);                              \
    CMP(0);                                                         \
    __syncthreads();                                                \
    STG(sA, 0, pa0, pa1, pa2, pa3, (2 * t + 2) * 64);               \
    STG(sB, 0, pb0, pb1, pb2, pb3, (2 * t + 2) * 64);               \
    __builtin_amdgcn_sched_barrier(0);                              \
    CMP(1);                                                         \
    __syncthreads();                                                \
  }                                                                 \
  STG(sA, 1, pa0, pa1, pa2, pa3, ((NTILE) - 1) * 64);               \
  STG(sB, 1, pb0, pb1, pb2, pb3, ((NTILE) - 1) * 64);               \
  __builtin_amdgcn_sched_barrier(0);                                \
  CMP(0);                                                           \
  __syncthreads();                                                  \
  CMP(1);

// ---------------- gemmA<1>: G = bf16(X@W1^T + b1)  (pre-activation stash) ----
// ---------------- gemmA<2>: G = bf16(silu(G) * (X@W2^T + b2)) ----------------
template<int MODE>
__global__ __launch_bounds__(512) void gemmA_k(
    const unsigned short* __restrict__ xb, const unsigned short* __restrict__ wb,
    const float* __restrict__ bias, const int* __restrict__ rtok,
    const int* __restrict__ counts, const int* __restrict__ ebase,
    const int* __restrict__ gbase, unsigned short* __restrict__ Gx, int e0) {
  int f = blockIdx.x + gridDim.x * (blockIdx.y + gridDim.y * blockIdx.z);
  int total = gridDim.x * gridDim.y * gridDim.z;
  int cpx = total >> 3;
  int nf = (f & 7) * cpx + (f >> 3);
  int pe = gridDim.x * gridDim.y;      // 256
  int ez = nf / pe;
  int r  = nf - ez * pe;
  int ntb = r >> 4;                    // gridDim.x == 16, mt fast
  int mt  = r & 15;

  const int e = e0 + ez;
  const int ce = counts[e];
  if (mt * 256 >= ce) return;
  const int rb = ebase[e];
  const int gb_ = gbase[e];
  const unsigned short* wt = wb + (size_t)ez * WELEM;
  const float* be = bias + (size_t)e * HID;

  __shared__ __attribute__((aligned(16))) unsigned short sA[2][256 * 64];
  __shared__ __attribute__((aligned(16))) unsigned short sB[2][256 * 64];

  const int tid = threadIdx.x;
  const int lane = tid & 63, wid = tid >> 6;
  const int wm = wid >> 2, wn = wid & 3;
  const unsigned stg = (unsigned)(wid * 1024);

  // staging sources: granule row = i*64 + (tid>>3); pre-swizzled col chunk
  const int grow = tid >> 3;
  const int lcol = ((tid & 7) ^ (grow & 7)) << 3;
  int sl0 = mt * 256 + grow;
  int c0 = sl0 < ce ? sl0 : ce - 1;
  int c1 = sl0 + 64 < ce ? sl0 + 64 : ce - 1;
  int c2 = sl0 + 128 < ce ? sl0 + 128 : ce - 1;
  int c3 = sl0 + 192 < ce ? sl0 + 192 : ce - 1;
  const unsigned short* pa0 = xb + (size_t)rtok[rb + c0] * DIM + lcol;
  const unsigned short* pa1 = xb + (size_t)rtok[rb + c1] * DIM + lcol;
  const unsigned short* pa2 = xb + (size_t)rtok[rb + c2] * DIM + lcol;
  const unsigned short* pa3 = xb + (size_t)rtok[rb + c3] * DIM + lcol;
  const unsigned short* pb0 = wt + (size_t)(ntb * 256 + grow) * DIM + lcol;
  const unsigned short* pb1 = pb0 + 64 * DIM;
  const unsigned short* pb2 = pb0 + 128 * DIM;
  const unsigned short* pb3 = pb0 + 192 * DIM;

  f32x4 acc[8][4] = {};
  GEMM_LOOP(16);   // K = 1024

#pragma unroll
  for (int n = 0; n < 4; ++n) {
    int col = ntb * 256 + wn * 64 + n * 16 + (lane & 15);
    float bb = be[col];
#pragma unroll
    for (int m = 0; m < 8; ++m) {
      int rbase = mt * 256 + wm * 128 + m * 16 + ((lane >> 4) << 2);
#pragma unroll
      for (int r2 = 0; r2 < 4; ++r2) {
        int slot = rbase + r2;
        if (slot < ce) {
          size_t gi = (size_t)(gb_ + slot) * HID + col;
          float h = acc[m][n][r2] + bb;
          if (MODE == 1) {
            Gx[gi] = f2bf(h);
          } else {
            float tv = bf2f(Gx[gi]);
            float sg = 1.0f / (1.0f + __expf(-tv));
            Gx[gi] = f2bf(tv * sg * h);
          }
        }
      }
    }
  }
}

// ---------------- gemm3n: out[token] += w*(G@Wp^T + bp), K=4096 ----------------
__global__ __launch_bounds__(512) void gemm3n_k(
    const unsigned short* __restrict__ Gx, const unsigned short* __restrict__ wpb,
    const float* __restrict__ bp, const int* __restrict__ rtok,
    const float* __restrict__ rwgt, const int* __restrict__ counts,
    const int* __restrict__ ebase, const int* __restrict__ gbase,
    float* __restrict__ out, int e0) {
  int f = blockIdx.x + gridDim.x * (blockIdx.y + gridDim.y * blockIdx.z);
  int total = gridDim.x * gridDim.y * gridDim.z;
  int cpx = total >> 3;
  int nf = (f & 7) * cpx + (f >> 3);
  int pe = gridDim.x * gridDim.y;      // 64
  int ez = nf / pe;
  int r  = nf - ez * pe;
  int ntb = r >> 4;                    // gridDim.x == 16, mt fast
  int mt  = r & 15;

  const int e = e0 + ez;
  const int ce = counts[e];
  if (mt * 256 >= ce) return;
  const int rb = ebase[e];
  const int gb_ = gbase[e];
  const unsigned short* wpt = wpb + (size_t)ez * WELEM;
  const float* bpe = bp + (size_t)e * DIM;

  __shared__ __attribute__((aligned(16))) unsigned short sA[2][256 * 64];
  __shared__ __attribute__((aligned(16))) unsigned short sB[2][256 * 64];

  const int tid = threadIdx.x;
  const int lane = tid & 63, wid = tid >> 6;
  const int wm = wid >> 2, wn = wid & 3;
  const unsigned stg = (unsigned)(wid * 1024);

  const int grow = tid >> 3;
  const int lcol = ((tid & 7) ^ (grow & 7)) << 3;
  const unsigned short* pa0 = Gx + (size_t)(gb_ + mt * 256 + grow) * HID + lcol;
  const unsigned short* pa1 = pa0 + (size_t)64 * HID;
  const unsigned short* pa2 = pa0 + (size_t)128 * HID;
  const unsigned short* pa3 = pa0 + (size_t)192 * HID;
  const unsigned short* pb0 = wpt + (size_t)(ntb * 256 + grow) * HID + lcol;
  const unsigned short* pb1 = pb0 + (size_t)64 * HID;
  const unsigned short* pb2 = pb0 + (size_t)128 * HID;
  const unsigned short* pb3 = pb0 + (size_t)192 * HID;

  f32x4 acc[8][4] = {};
  GEMM_LOOP(64);   // K = 4096

#pragma unroll
  for (int n = 0; n < 4; ++n) {
    int col = ntb * 256 + wn * 64 + n * 16 + (lane & 15);
    float bb = bpe[col];
#pragma unroll
    for (int m = 0; m < 8; ++m) {
      int rbase = mt * 256 + wm * 128 + m * 16 + ((lane >> 4) << 2);
#pragma unroll
      for (int r2 = 0; r2 < 4; ++r2) {
        int slot = rbase + r2;
        if (slot < ce) {
          int tok = rtok[rb + slot];
          float w = rwgt[rb + slot];
          atomicAdd(out + (size_t)tok * DIM + col, w * (acc[m][n][r2] + bb));
        }
      }
    }
  }
}

// ---------------- host ----------------
extern "C" void kernel_launch(void* const* d_in, const int* in_sizes, int n_in,
                              void* d_out, int out_size, void* d_ws, size_t ws_size,
                              hipStream_t stream) {
  const float* x  = (const float*)d_in[0];
  const float* gw = (const float*)d_in[1];
  const float* gb = (const float*)d_in[2];
  const float* w1 = (const float*)d_in[3];
  const float* b1 = (const float*)d_in[4];
  const float* w2 = (const float*)d_in[5];
  const float* b2 = (const float*)d_in[6];
  const float* wp = (const float*)d_in[7];
  const float* bp = (const float*)d_in[8];
  float* out = (float*)d_out;

  char* ws = (char*)d_ws;
  const size_t BIG_NEED = 352551008ull;
  bool big = ws_size >= BIG_NEED;

  unsigned short* xb = (unsigned short*)ws;                       // 16 MB
  unsigned short *Gp, *w1a, *w2a, *wpa;
  int* tassign; float2* tprob; int* rtok; float* rwgt; int* meta;
  if (big) {
    Gp  = (unsigned short*)(ws + 16777216);      // 134.2 MB (16384 global slots)
    w1a = (unsigned short*)(ws + 150994944);     // 64 MB
    w2a = (unsigned short*)(ws + 218103808);     // 64 MB
    wpa = (unsigned short*)(ws + 285212672);     // 64 MB
    tassign = (int*)(ws + 352321536);
    tprob   = (float2*)(ws + 352354304);
    rtok    = (int*)(ws + 352419840);
    rwgt    = (float*)(ws + 352485376);
    meta    = (int*)(ws + 352550912);            // counts[8], ebase[8], zbase[8]
  } else {
    Gp  = (unsigned short*)(ws + 16777216);      // 64 MB (local slots)
    w1a = (unsigned short*)(ws + 83886080);      // 8 MB per-expert
    w2a = (unsigned short*)(ws + 92274688);
    wpa = (unsigned short*)(ws + 100663296);
    tassign = (int*)(ws + 109051904);
    tprob   = (float2*)(ws + 109084672);
    rtok    = (int*)(ws + 109150208);
    rwgt    = (float*)(ws + 109215744);
    meta    = (int*)(ws + 109281280);
  }
  int* counts = meta;
  int* ebase  = meta + 8;
  int* zbase  = meta + 16;

  hipMemsetAsync(meta, 0, 96, stream);
  hipMemsetAsync(out, 0, (size_t)(N_TOK * DIM + 1) * sizeof(float), stream);

  convert_x_k<<<4096, 256, 0, stream>>>(x, xb);
  gate2_k<<<N_TOK / 4, 256, 0, stream>>>(x, gw, gb, tassign, tprob);
  route_k<<<1, 256, 0, stream>>>(tassign, tprob, rtok, rwgt, counts, ebase);
  aux_k<<<1, 64, 0, stream>>>(counts, out);

  if (big) {
    tcvt_k<<<dim3(4096, 3, NEXP), 256, 0, stream>>>(w1, w2, wp, w1a, w2a, wpa);
    gemmA_k<1><<<dim3(16, 16, NEXP), 512, 0, stream>>>(
        xb, w1a, b1, rtok, counts, ebase, ebase, Gp, 0);
    gemmA_k<2><<<dim3(16, 16, NEXP), 512, 0, stream>>>(
        xb, w2a, b2, rtok, counts, ebase, ebase, Gp, 0);
    gemm3n_k<<<dim3(16, 4, NEXP), 512, 0, stream>>>(
        Gp, wpa, bp, rtok, rwgt, counts, ebase, ebase, out, 0);
  } else {
    for (int e = 0; e < NEXP; ++e) {
      tcvt_k<<<dim3(4096, 3, 1), 256, 0, stream>>>(
          w1 + (size_t)e * WELEM, w2 + (size_t)e * WELEM, wp + (size_t)e * WELEM,
          w1a, w2a, wpa);
      gemmA_k<1><<<dim3(16, 16, 1), 512, 0, stream>>>(
          xb, w1a, b1, rtok, counts, ebase, zbase, Gp, e);
      gemmA_k<2><<<dim3(16, 16, 1), 512, 0, stream>>>(
          xb, w2a, b2, rtok, counts, ebase, zbase, Gp, e);
      gemm3n_k<<<dim3(16, 4, 1), 512, 0, stream>>>(
          Gp, wpa, bp, rtok, rwgt, counts, ebase, zbase, out, e);
    }
  }
}

// Round 8
// 1301.495 us; speedup vs baseline: 1.0036x; 1.0010x over previous
//
#include <hip/hip_runtime.h>
#include <cstdint>
#include <cstddef>

#define N_TOK 8192
#define DIM   1024
#define NEXP  8
#define HID   4096
#define WELEM 4194304ull   // D*H elements per expert matrix

typedef __attribute__((ext_vector_type(8))) short short8v;
typedef __attribute__((ext_vector_type(4))) float f32x4;

__device__ __forceinline__ unsigned short f2bf(float f) {
  unsigned u = __builtin_bit_cast(unsigned, f);
  u += 0x7fffu + ((u >> 16) & 1u);     // RNE
  return (unsigned short)(u >> 16);
}
__device__ __forceinline__ float bf2f(unsigned short u) {
  return __builtin_bit_cast(float, (unsigned)u << 16);
}

__device__ __forceinline__ void gload16(const void* g, void* l) {
  __builtin_amdgcn_global_load_lds(
      (const __attribute__((address_space(1))) void*)g,
      (__attribute__((address_space(3))) void*)l, 16, 0, 0);
}

// ---------------- x fp32 -> bf16 ----------------
__global__ void convert_x_k(const float* __restrict__ x, unsigned short* __restrict__ xb) {
  size_t i = ((size_t)blockIdx.x * 256 + threadIdx.x) * 8;
  float4 a = *(const float4*)(x + i);
  float4 b = *(const float4*)(x + i + 4);
  short8v v;
  v[0] = (short)f2bf(a.x); v[1] = (short)f2bf(a.y); v[2] = (short)f2bf(a.z); v[3] = (short)f2bf(a.w);
  v[4] = (short)f2bf(b.x); v[5] = (short)f2bf(b.y); v[6] = (short)f2bf(b.z); v[7] = (short)f2bf(b.w);
  *(short8v*)(xb + i) = v;
}

// ---------------- gate: fp32 logits, top-2, softmax (NO atomics) ----------------
__global__ void gate2_k(const float* __restrict__ x, const float* __restrict__ gw,
                        const float* __restrict__ gb, int* __restrict__ tassign,
                        float2* __restrict__ tprob) {
  int lane = threadIdx.x & 63, wid = threadIdx.x >> 6;
  int t = blockIdx.x * 4 + wid;
  const float* xr = x + (size_t)t * DIM;
  float acc[NEXP];
#pragma unroll
  for (int e = 0; e < NEXP; ++e) acc[e] = 0.f;
#pragma unroll
  for (int j = 0; j < DIM / 256; ++j) {
    int d0 = j * 256 + lane * 4;
    float4 xv = *(const float4*)(xr + d0);
    const float* gp = gw + (size_t)d0 * NEXP;
#pragma unroll
    for (int c = 0; c < 4; ++c) {
      float xs = (c == 0) ? xv.x : (c == 1) ? xv.y : (c == 2) ? xv.z : xv.w;
      float4 g0 = *(const float4*)(gp + c * NEXP);
      float4 g1 = *(const float4*)(gp + c * NEXP + 4);
      acc[0] += xs * g0.x; acc[1] += xs * g0.y; acc[2] += xs * g0.z; acc[3] += xs * g0.w;
      acc[4] += xs * g1.x; acc[5] += xs * g1.y; acc[6] += xs * g1.z; acc[7] += xs * g1.w;
    }
  }
#pragma unroll
  for (int e = 0; e < NEXP; ++e) {
    float v = acc[e];
#pragma unroll
    for (int s = 1; s < 64; s <<= 1) v += __shfl_xor(v, s);
    acc[e] = v;
  }
  if (lane == 0) {
    float lg[NEXP];
#pragma unroll
    for (int e = 0; e < NEXP; ++e) lg[e] = acc[e] + gb[e];
    int i0 = 0;
#pragma unroll
    for (int e = 1; e < NEXP; ++e) if (lg[e] > lg[i0]) i0 = e;
    int i1 = -1;
#pragma unroll
    for (int e = 0; e < NEXP; ++e) if (e != i0 && (i1 < 0 || lg[e] > lg[i1])) i1 = e;
    float ex = expf(lg[i1] - lg[i0]);       // <= 1
    float p0 = 1.f / (1.f + ex);
    float p1 = ex * p0;
    tassign[t] = i0 | (i1 << 8);
    tprob[t] = make_float2(p0, p1);
  }
}

// ---------------- routing: single block, LDS atomics only ----------------
__global__ void route_k(const int* __restrict__ tassign, const float2* __restrict__ tprob,
                        int* __restrict__ rtok, float* __restrict__ rwgt,
                        int* __restrict__ counts, int* __restrict__ ebase) {
  __shared__ int h[NEXP];
  __shared__ int cur[NEXP];
  int tid = threadIdx.x;
  if (tid < NEXP) h[tid] = 0;
  __syncthreads();
  for (int t = tid; t < N_TOK; t += 256) {
    int a = tassign[t];
    atomicAdd(&h[a & 255], 1);
    atomicAdd(&h[(a >> 8) & 255], 1);
  }
  __syncthreads();
  if (tid == 0) {
    int b = 0;
    for (int e = 0; e < NEXP; ++e) { counts[e] = h[e]; ebase[e] = b; cur[e] = b; b += h[e]; }
  }
  __syncthreads();
  for (int t = tid; t < N_TOK; t += 256) {
    int a = tassign[t];
    float2 p = tprob[t];
    int p0 = atomicAdd(&cur[a & 255], 1);
    rtok[p0] = t; rwgt[p0] = p.x;
    int p1 = atomicAdd(&cur[(a >> 8) & 255], 1);
    rtok[p1] = t; rwgt[p1] = p.y;
  }
}

// ---------------- aux loss ----------------
__global__ void aux_k(const int* __restrict__ counts, float* __restrict__ out) {
  if (threadIdx.x == 0) {
    float tot = 0.f, c[NEXP];
    for (int e = 0; e < NEXP; ++e) { c[e] = (float)counts[e]; tot += c[e]; }
    float a = 0.f;
    for (int e = 0; e < NEXP; ++e) { float d = c[e] / tot - 0.125f; a += d * d; }
    out[(size_t)N_TOK * DIM] = a;
  }
}

// ---------------- transpose + fp32->bf16; grid (4096 tiles, 3 mats, nexp) ----------------
__global__ void tcvt_k(const float* __restrict__ w1, const float* __restrict__ w2,
                       const float* __restrict__ wp, unsigned short* __restrict__ d1,
                       unsigned short* __restrict__ d2, unsigned short* __restrict__ d3) {
  int tile = blockIdx.x, mat = blockIdx.y;
  size_t eo = (size_t)blockIdx.z * WELEM;
  const float* src; unsigned short* dst; int R, C;
  if (mat == 0)      { src = w1 + eo; dst = d1 + eo; R = DIM; C = HID; }
  else if (mat == 1) { src = w2 + eo; dst = d2 + eo; R = DIM; C = HID; }
  else               { src = wp + eo; dst = d3 + eo; R = HID; C = DIM; }
  int tilesC = C >> 5;
  int tr = (tile / tilesC) << 5;
  int tc = (tile % tilesC) << 5;
  __shared__ float tl[32][33];
  int tx = threadIdx.x & 31, ty = threadIdx.x >> 5;
#pragma unroll
  for (int i = 0; i < 32; i += 8) tl[ty + i][tx] = src[(size_t)(tr + ty + i) * C + tc + tx];
  __syncthreads();
#pragma unroll
  for (int i = 0; i < 32; i += 8) dst[(size_t)(tc + ty + i) * R + tr + tx] = f2bf(tl[tx][ty + i]);
}

// ================= 256x256 2-phase GEMM core =================
// 512 threads, 8 waves (2M x 4N), wave tile 128x64, BK=64,
// sA/sB double-buffered 128KB LDS, XOR-swizzled both sides.
// __launch_bounds__(512, 2): LDS already caps at 1 block/CU (2 waves/EU);
// declare it so the VGPR cap is 256 (acc128+af32+bf16+addr~210) -> no spill.
#define STG(SD, BUFI, P0, P1, P2, P3, K0)                           \
  gload16(P0 + (K0), (char*)SD[BUFI] + stg);                        \
  gload16(P1 + (K0), (char*)SD[BUFI] + stg + 8192);                 \
  gload16(P2 + (K0), (char*)SD[BUFI] + stg + 16384);                \
  gload16(P3 + (K0), (char*)SD[BUFI] + stg + 24576);

#define CMP(BUFI)                                                   \
  {                                                                 \
    _Pragma("unroll")                                               \
    for (int s = 0; s < 2; ++s) {                                   \
      short8v af[8], bf[4];                                         \
      _Pragma("unroll")                                             \
      for (int m = 0; m < 8; ++m) {                                 \
        int row = wm * 128 + m * 16 + (lane & 15);                  \
        int p = (s * 4 + (lane >> 4)) ^ (row & 7);                  \
        af[m] = *(const short8v*)((const char*)sA[BUFI] + row * 128 + p * 16); \
      }                                                             \
      _Pragma("unroll")                                             \
      for (int n = 0; n < 4; ++n) {                                 \
        int row = wn * 64 + n * 16 + (lane & 15);                   \
        int p = (s * 4 + (lane >> 4)) ^ (row & 7);                  \
        bf[n] = *(const short8v*)((const char*)sB[BUFI] + row * 128 + p * 16); \
      }                                                             \
      _Pragma("unroll")                                             \
      for (int m = 0; m < 8; ++m)                                   \
        _Pragma("unroll")                                           \
        for (int n = 0; n < 4; ++n)                                 \
          acc[m][n] = __builtin_amdgcn_mfma_f32_16x16x32_bf16(af[m], bf[n], acc[m][n], 0, 0, 0); \
    }                                                               \
  }

#define GEMM_LOOP(NTILE)                                            \
  STG(sA, 0, pa0, pa1, pa2, pa3, 0);                                \
  STG(sB, 0, pb0, pb1, pb2, pb3, 0);                                \
  __syncthreads();                                                  \
  _Pragma("unroll 1")                                               \
  for (int t = 0; t < (NTILE) / 2 - 1; ++t) {                       \
    STG(sA, 1, pa0, pa1, pa2, pa3, (2 * t + 1) * 64);               \
    STG(sB, 1, pb0, pb1, pb2, pb3, (2 * t + 1) * 64);               \
    __builtin_amdgcn_sched_barrier(0);                              \
    CMP(0);                                                         \
    __syncthreads();                                                \
    STG(sA, 0, pa0, pa1, pa2, pa3, (2 * t + 2) * 64);               \
    STG(sB, 0, pb0, pb1, pb2, pb3, (2 * t + 2) * 64);               \
    __builtin_amdgcn_sched_barrier(0);                              \
    CMP(1);                                                         \
    __syncthreads();                                                \
  }                                                                 \
  STG(sA, 1, pa0, pa1, pa2, pa3, ((NTILE) - 1) * 64);               \
  STG(sB, 1, pb0, pb1, pb2, pb3, ((NTILE) - 1) * 64);               \
  __builtin_amdgcn_sched_barrier(0);                                \
  CMP(0);                                                           \
  __syncthreads();                                                  \
  CMP(1);

// ---------------- gemmA<1>: G = bf16(X@W1^T + b1)  (pre-activation stash) ----
// ---------------- gemmA<2>: G = bf16(silu(G) * (X@W2^T + b2)) ----------------
template<int MODE>
__global__ __launch_bounds__(512, 2) void gemmA_k(
    const unsigned short* __restrict__ xb, const unsigned short* __restrict__ wb,
    const float* __restrict__ bias, const int* __restrict__ rtok,
    const int* __restrict__ counts, const int* __restrict__ ebase,
    const int* __restrict__ gbase, unsigned short* __restrict__ Gx, int e0) {
  int f = blockIdx.x + gridDim.x * (blockIdx.y + gridDim.y * blockIdx.z);
  int total = gridDim.x * gridDim.y * gridDim.z;
  int cpx = total >> 3;
  int nf = (f & 7) * cpx + (f >> 3);
  int pe = gridDim.x * gridDim.y;      // 256
  int ez = nf / pe;
  int r  = nf - ez * pe;
  int ntb = r >> 4;                    // gridDim.x == 16, mt fast
  int mt  = r & 15;

  const int e = e0 + ez;
  const int ce = counts[e];
  if (mt * 256 >= ce) return;
  const int rb = ebase[e];
  const int gb_ = gbase[e];
  const unsigned short* wt = wb + (size_t)ez * WELEM;
  const float* be = bias + (size_t)e * HID;

  __shared__ __attribute__((aligned(16))) unsigned short sA[2][256 * 64];
  __shared__ __attribute__((aligned(16))) unsigned short sB[2][256 * 64];

  const int tid = threadIdx.x;
  const int lane = tid & 63, wid = tid >> 6;
  const int wm = wid >> 2, wn = wid & 3;
  const unsigned stg = (unsigned)(wid * 1024);

  // staging sources: granule row = i*64 + (tid>>3); pre-swizzled col chunk
  const int grow = tid >> 3;
  const int lcol = ((tid & 7) ^ (grow & 7)) << 3;
  int sl0 = mt * 256 + grow;
  int c0 = sl0 < ce ? sl0 : ce - 1;
  int c1 = sl0 + 64 < ce ? sl0 + 64 : ce - 1;
  int c2 = sl0 + 128 < ce ? sl0 + 128 : ce - 1;
  int c3 = sl0 + 192 < ce ? sl0 + 192 : ce - 1;
  const unsigned short* pa0 = xb + (size_t)rtok[rb + c0] * DIM + lcol;
  const unsigned short* pa1 = xb + (size_t)rtok[rb + c1] * DIM + lcol;
  const unsigned short* pa2 = xb + (size_t)rtok[rb + c2] * DIM + lcol;
  const unsigned short* pa3 = xb + (size_t)rtok[rb + c3] * DIM + lcol;
  const unsigned short* pb0 = wt + (size_t)(ntb * 256 + grow) * DIM + lcol;
  const unsigned short* pb1 = pb0 + 64 * DIM;
  const unsigned short* pb2 = pb0 + 128 * DIM;
  const unsigned short* pb3 = pb0 + 192 * DIM;

  f32x4 acc[8][4] = {};
  GEMM_LOOP(16);   // K = 1024

#pragma unroll
  for (int n = 0; n < 4; ++n) {
    int col = ntb * 256 + wn * 64 + n * 16 + (lane & 15);
    float bb = be[col];
#pragma unroll
    for (int m = 0; m < 8; ++m) {
      int rbase = mt * 256 + wm * 128 + m * 16 + ((lane >> 4) << 2);
#pragma unroll
      for (int r2 = 0; r2 < 4; ++r2) {
        int slot = rbase + r2;
        if (slot < ce) {
          size_t gi = (size_t)(gb_ + slot) * HID + col;
          float h = acc[m][n][r2] + bb;
          if (MODE == 1) {
            Gx[gi] = f2bf(h);
          } else {
            float tv = bf2f(Gx[gi]);
            float sg = 1.0f / (1.0f + __expf(-tv));
            Gx[gi] = f2bf(tv * sg * h);
          }
        }
      }
    }
  }
}

// ---------------- gemm3n: out[token] += w*(G@Wp^T + bp), K=4096 ----------------
__global__ __launch_bounds__(512, 2) void gemm3n_k(
    const unsigned short* __restrict__ Gx, const unsigned short* __restrict__ wpb,
    const float* __restrict__ bp, const int* __restrict__ rtok,
    const float* __restrict__ rwgt, const int* __restrict__ counts,
    const int* __restrict__ ebase, const int* __restrict__ gbase,
    float* __restrict__ out, int e0) {
  int f = blockIdx.x + gridDim.x * (blockIdx.y + gridDim.y * blockIdx.z);
  int total = gridDim.x * gridDim.y * gridDim.z;
  int cpx = total >> 3;
  int nf = (f & 7) * cpx + (f >> 3);
  int pe = gridDim.x * gridDim.y;      // 64
  int ez = nf / pe;
  int r  = nf - ez * pe;
  int ntb = r >> 4;                    // gridDim.x == 16, mt fast
  int mt  = r & 15;

  const int e = e0 + ez;
  const int ce = counts[e];
  if (mt * 256 >= ce) return;
  const int rb = ebase[e];
  const int gb_ = gbase[e];
  const unsigned short* wpt = wpb + (size_t)ez * WELEM;
  const float* bpe = bp + (size_t)e * DIM;

  __shared__ __attribute__((aligned(16))) unsigned short sA[2][256 * 64];
  __shared__ __attribute__((aligned(16))) unsigned short sB[2][256 * 64];

  const int tid = threadIdx.x;
  const int lane = tid & 63, wid = tid >> 6;
  const int wm = wid >> 2, wn = wid & 3;
  const unsigned stg = (unsigned)(wid * 1024);

  const int grow = tid >> 3;
  const int lcol = ((tid & 7) ^ (grow & 7)) << 3;
  const unsigned short* pa0 = Gx + (size_t)(gb_ + mt * 256 + grow) * HID + lcol;
  const unsigned short* pa1 = pa0 + (size_t)64 * HID;
  const unsigned short* pa2 = pa0 + (size_t)128 * HID;
  const unsigned short* pa3 = pa0 + (size_t)192 * HID;
  const unsigned short* pb0 = wpt + (size_t)(ntb * 256 + grow) * HID + lcol;
  const unsigned short* pb1 = pb0 + (size_t)64 * HID;
  const unsigned short* pb2 = pb0 + (size_t)128 * HID;
  const unsigned short* pb3 = pb0 + (size_t)192 * HID;

  f32x4 acc[8][4] = {};
  GEMM_LOOP(64);   // K = 4096

#pragma unroll
  for (int n = 0; n < 4; ++n) {
    int col = ntb * 256 + wn * 64 + n * 16 + (lane & 15);
    float bb = bpe[col];
#pragma unroll
    for (int m = 0; m < 8; ++m) {
      int rbase = mt * 256 + wm * 128 + m * 16 + ((lane >> 4) << 2);
#pragma unroll
      for (int r2 = 0; r2 < 4; ++r2) {
        int slot = rbase + r2;
        if (slot < ce) {
          int tok = rtok[rb + slot];
          float w = rwgt[rb + slot];
          atomicAdd(out + (size_t)tok * DIM + col, w * (acc[m][n][r2] + bb));
        }
      }
    }
  }
}

// ---------------- host ----------------
extern "C" void kernel_launch(void* const* d_in, const int* in_sizes, int n_in,
                              void* d_out, int out_size, void* d_ws, size_t ws_size,
                              hipStream_t stream) {
  const float* x  = (const float*)d_in[0];
  const float* gw = (const float*)d_in[1];
  const float* gb = (const float*)d_in[2];
  const float* w1 = (const float*)d_in[3];
  const float* b1 = (const float*)d_in[4];
  const float* w2 = (const float*)d_in[5];
  const float* b2 = (const float*)d_in[6];
  const float* wp = (const float*)d_in[7];
  const float* bp = (const float*)d_in[8];
  float* out = (float*)d_out;

  char* ws = (char*)d_ws;
  const size_t BIG_NEED = 352551008ull;
  bool big = ws_size >= BIG_NEED;

  unsigned short* xb = (unsigned short*)ws;                       // 16 MB
  unsigned short *Gp, *w1a, *w2a, *wpa;
  int* tassign; float2* tprob; int* rtok; float* rwgt; int* meta;
  if (big) {
    Gp  = (unsigned short*)(ws + 16777216);      // 134.2 MB (16384 global slots)
    w1a = (unsigned short*)(ws + 150994944);     // 64 MB
    w2a = (unsigned short*)(ws + 218103808);     // 64 MB
    wpa = (unsigned short*)(ws + 285212672);     // 64 MB
    tassign = (int*)(ws + 352321536);
    tprob   = (float2*)(ws + 352354304);
    rtok    = (int*)(ws + 352419840);
    rwgt    = (float*)(ws + 352485376);
    meta    = (int*)(ws + 352550912);            // counts[8], ebase[8], zbase[8]
  } else {
    Gp  = (unsigned short*)(ws + 16777216);      // 64 MB (local slots)
    w1a = (unsigned short*)(ws + 83886080);      // 8 MB per-expert
    w2a = (unsigned short*)(ws + 92274688);
    wpa = (unsigned short*)(ws + 100663296);
    tassign = (int*)(ws + 109051904);
    tprob   = (float2*)(ws + 109084672);
    rtok    = (int*)(ws + 109150208);
    rwgt    = (float*)(ws + 109215744);
    meta    = (int*)(ws + 109281280);
  }
  int* counts = meta;
  int* ebase  = meta + 8;
  int* zbase  = meta + 16;

  hipMemsetAsync(meta, 0, 96, stream);
  hipMemsetAsync(out, 0, (size_t)(N_TOK * DIM + 1) * sizeof(float), stream);

  convert_x_k<<<4096, 256, 0, stream>>>(x, xb);
  gate2_k<<<N_TOK / 4, 256, 0, stream>>>(x, gw, gb, tassign, tprob);
  route_k<<<1, 256, 0, stream>>>(tassign, tprob, rtok, rwgt, counts, ebase);
  aux_k<<<1, 64, 0, stream>>>(counts, out);

  if (big) {
    tcvt_k<<<dim3(4096, 3, NEXP), 256, 0, stream>>>(w1, w2, wp, w1a, w2a, wpa);
    gemmA_k<1><<<dim3(16, 16, NEXP), 512, 0, stream>>>(
        xb, w1a, b1, rtok, counts, ebase, ebase, Gp, 0);
    gemmA_k<2><<<dim3(16, 16, NEXP), 512, 0, stream>>>(
        xb, w2a, b2, rtok, counts, ebase, ebase, Gp, 0);
    gemm3n_k<<<dim3(16, 4, NEXP), 512, 0, stream>>>(
        Gp, wpa, bp, rtok, rwgt, counts, ebase, ebase, out, 0);
  } else {
    for (int e = 0; e < NEXP; ++e) {
      tcvt_k<<<dim3(4096, 3, 1), 256, 0, stream>>>(
          w1 + (size_t)e * WELEM, w2 + (size_t)e * WELEM, wp + (size_t)e * WELEM,
          w1a, w2a, wpa);
      gemmA_k<1><<<dim3(16, 16, 1), 512, 0, stream>>>(
          xb, w1a, b1, rtok, counts, ebase, zbase, Gp, e);
      gemmA_k<2><<<dim3(16, 16, 1), 512, 0, stream>>>(
          xb, w2a, b2, rtok, counts, ebase, zbase, Gp, e);
      gemm3n_k<<<dim3(16, 4, 1), 512, 0, stream>>>(
          Gp, wpa, bp, rtok, rwgt, counts, ebase, zbase, out, e);
    }
  }
}

// Round 11
// 1238.654 us; speedup vs baseline: 1.0545x; 1.0507x over previous
//
#include <hip/hip_runtime.h>
#include <cstdint>
#include <cstddef>

#define N_TOK 8192
#define DIM   1024
#define NEXP  8
#define HID   4096
#define WELEM 4194304ull   // D*H elements per expert matrix

typedef __attribute__((ext_vector_type(8))) short short8v;
typedef __attribute__((ext_vector_type(4))) float f32x4;

__device__ __forceinline__ unsigned short f2bf(float f) {
  unsigned u = __builtin_bit_cast(unsigned, f);
  u += 0x7fffu + ((u >> 16) & 1u);     // RNE
  return (unsigned short)(u >> 16);
}
__device__ __forceinline__ float bf2f(unsigned short u) {
  return __builtin_bit_cast(float, (unsigned)u << 16);
}

__device__ __forceinline__ void gload16(const void* g, void* l) {
  __builtin_amdgcn_global_load_lds(
      (const __attribute__((address_space(1))) void*)g,
      (__attribute__((address_space(3))) void*)l, 16, 0, 0);
}

// ---------------- x fp32 -> bf16 ----------------
__global__ void convert_x_k(const float* __restrict__ x, unsigned short* __restrict__ xb) {
  size_t i = ((size_t)blockIdx.x * 256 + threadIdx.x) * 8;
  float4 a = *(const float4*)(x + i);
  float4 b = *(const float4*)(x + i + 4);
  short8v v;
  v[0] = (short)f2bf(a.x); v[1] = (short)f2bf(a.y); v[2] = (short)f2bf(a.z); v[3] = (short)f2bf(a.w);
  v[4] = (short)f2bf(b.x); v[5] = (short)f2bf(b.y); v[6] = (short)f2bf(b.z); v[7] = (short)f2bf(b.w);
  *(short8v*)(xb + i) = v;
}

// ---------------- gate: fp32 logits, top-2, softmax (NO atomics) ----------------
__global__ void gate2_k(const float* __restrict__ x, const float* __restrict__ gw,
                        const float* __restrict__ gb, int* __restrict__ tassign,
                        float2* __restrict__ tprob) {
  int lane = threadIdx.x & 63, wid = threadIdx.x >> 6;
  int t = blockIdx.x * 4 + wid;
  const float* xr = x + (size_t)t * DIM;
  float acc[NEXP];
#pragma unroll
  for (int e = 0; e < NEXP; ++e) acc[e] = 0.f;
#pragma unroll
  for (int j = 0; j < DIM / 256; ++j) {
    int d0 = j * 256 + lane * 4;
    float4 xv = *(const float4*)(xr + d0);
    const float* gp = gw + (size_t)d0 * NEXP;
#pragma unroll
    for (int c = 0; c < 4; ++c) {
      float xs = (c == 0) ? xv.x : (c == 1) ? xv.y : (c == 2) ? xv.z : xv.w;
      float4 g0 = *(const float4*)(gp + c * NEXP);
      float4 g1 = *(const float4*)(gp + c * NEXP + 4);
      acc[0] += xs * g0.x; acc[1] += xs * g0.y; acc[2] += xs * g0.z; acc[3] += xs * g0.w;
      acc[4] += xs * g1.x; acc[5] += xs * g1.y; acc[6] += xs * g1.z; acc[7] += xs * g1.w;
    }
  }
#pragma unroll
  for (int e = 0; e < NEXP; ++e) {
    float v = acc[e];
#pragma unroll
    for (int s = 1; s < 64; s <<= 1) v += __shfl_xor(v, s);
    acc[e] = v;
  }
  if (lane == 0) {
    float lg[NEXP];
#pragma unroll
    for (int e = 0; e < NEXP; ++e) lg[e] = acc[e] + gb[e];
    int i0 = 0;
#pragma unroll
    for (int e = 1; e < NEXP; ++e) if (lg[e] > lg[i0]) i0 = e;
    int i1 = -1;
#pragma unroll
    for (int e = 0; e < NEXP; ++e) if (e != i0 && (i1 < 0 || lg[e] > lg[i1])) i1 = e;
    float ex = expf(lg[i1] - lg[i0]);       // <= 1
    float p0 = 1.f / (1.f + ex);
    float p1 = ex * p0;
    tassign[t] = i0 | (i1 << 8);
    tprob[t] = make_float2(p0, p1);
  }
}

// ---------------- routing: single block, LDS atomics only ----------------
__global__ void route_k(const int* __restrict__ tassign, const float2* __restrict__ tprob,
                        int* __restrict__ rtok, float* __restrict__ rwgt,
                        int* __restrict__ counts, int* __restrict__ ebase) {
  __shared__ int h[NEXP];
  __shared__ int cur[NEXP];
  int tid = threadIdx.x;
  if (tid < NEXP) h[tid] = 0;
  __syncthreads();
  for (int t = tid; t < N_TOK; t += 256) {
    int a = tassign[t];
    atomicAdd(&h[a & 255], 1);
    atomicAdd(&h[(a >> 8) & 255], 1);
  }
  __syncthreads();
  if (tid == 0) {
    int b = 0;
    for (int e = 0; e < NEXP; ++e) { counts[e] = h[e]; ebase[e] = b; cur[e] = b; b += h[e]; }
  }
  __syncthreads();
  for (int t = tid; t < N_TOK; t += 256) {
    int a = tassign[t];
    float2 p = tprob[t];
    int p0 = atomicAdd(&cur[a & 255], 1);
    rtok[p0] = t; rwgt[p0] = p.x;
    int p1 = atomicAdd(&cur[(a >> 8) & 255], 1);
    rtok[p1] = t; rwgt[p1] = p.y;
  }
}

// ---------------- aux loss ----------------
__global__ void aux_k(const int* __restrict__ counts, float* __restrict__ out) {
  if (threadIdx.x == 0) {
    float tot = 0.f, c[NEXP];
    for (int e = 0; e < NEXP; ++e) { c[e] = (float)counts[e]; tot += c[e]; }
    float a = 0.f;
    for (int e = 0; e < NEXP; ++e) { float d = c[e] / tot - 0.125f; a += d * d; }
    out[(size_t)N_TOK * DIM] = a;
  }
}

// ---------------- transpose + fp32->bf16; grid (4096 tiles, 3 mats, nexp) ----------------
__global__ void tcvt_k(const float* __restrict__ w1, const float* __restrict__ w2,
                       const float* __restrict__ wp, unsigned short* __restrict__ d1,
                       unsigned short* __restrict__ d2, unsigned short* __restrict__ d3) {
  int tile = blockIdx.x, mat = blockIdx.y;
  size_t eo = (size_t)blockIdx.z * WELEM;
  const float* src; unsigned short* dst; int R, C;
  if (mat == 0)      { src = w1 + eo; dst = d1 + eo; R = DIM; C = HID; }
  else if (mat == 1) { src = w2 + eo; dst = d2 + eo; R = DIM; C = HID; }
  else               { src = wp + eo; dst = d3 + eo; R = HID; C = DIM; }
  int tilesC = C >> 5;
  int tr = (tile / tilesC) << 5;
  int tc = (tile % tilesC) << 5;
  __shared__ float tl[32][33];
  int tx = threadIdx.x & 31, ty = threadIdx.x >> 5;
#pragma unroll
  for (int i = 0; i < 32; i += 8) tl[ty + i][tx] = src[(size_t)(tr + ty + i) * C + tc + tx];
  __syncthreads();
#pragma unroll
  for (int i = 0; i < 32; i += 8) dst[(size_t)(tc + ty + i) * R + tr + tx] = f2bf(tl[tx][ty + i]);
}

// ================= 128x128 2-phase GEMM core =================
// 256 threads, 4 waves (2M x 2N), wave tile 64x64, BK=64,
// sA/sB double-buffered 64KB LDS -> 2 blocks/CU (co-resident block hides the
// per-K-step barrier drain), XOR-swizzled both sides.
#define STG(SD, BUFI, P0, P1, P2, P3, K0)                           \
  gload16(P0 + (K0), (char*)SD[BUFI] + stg);                        \
  gload16(P1 + (K0), (char*)SD[BUFI] + stg + 4096);                 \
  gload16(P2 + (K0), (char*)SD[BUFI] + stg + 8192);                 \
  gload16(P3 + (K0), (char*)SD[BUFI] + stg + 12288);

#define CMP(BUFI)                                                   \
  {                                                                 \
    _Pragma("unroll")                                               \
    for (int s = 0; s < 2; ++s) {                                   \
      short8v af[4], bf[4];                                         \
      _Pragma("unroll")                                             \
      for (int m = 0; m < 4; ++m) {                                 \
        int row = wm * 64 + m * 16 + (lane & 15);                   \
        int p = (s * 4 + (lane >> 4)) ^ (row & 7);                  \
        af[m] = *(const short8v*)((const char*)sA[BUFI] + row * 128 + p * 16); \
      }                                                             \
      _Pragma("unroll")                                             \
      for (int n = 0; n < 4; ++n) {                                 \
        int row = wn * 64 + n * 16 + (lane & 15);                   \
        int p = (s * 4 + (lane >> 4)) ^ (row & 7);                  \
        bf[n] = *(const short8v*)((const char*)sB[BUFI] + row * 128 + p * 16); \
      }                                                             \
      _Pragma("unroll")                                             \
      for (int m = 0; m < 4; ++m)                                   \
        _Pragma("unroll")                                           \
        for (int n = 0; n < 4; ++n)                                 \
          acc[m][n] = __builtin_amdgcn_mfma_f32_16x16x32_bf16(af[m], bf[n], acc[m][n], 0, 0, 0); \
    }                                                               \
  }

#define GEMM_LOOP(NTILE)                                            \
  STG(sA, 0, pa0, pa1, pa2, pa3, 0);                                \
  STG(sB, 0, pb0, pb1, pb2, pb3, 0);                                \
  __syncthreads();                                                  \
  _Pragma("unroll 1")                                               \
  for (int t = 0; t < (NTILE) / 2 - 1; ++t) {                       \
    STG(sA, 1, pa0, pa1, pa2, pa3, (2 * t + 1) * 64);               \
    STG(sB, 1, pb0, pb1, pb2, pb3, (2 * t + 1) * 64);               \
    __builtin_amdgcn_sched_barrier(0);                              \
    CMP(0);                                                         \
    __syncthreads();                                                \
    STG(sA, 0, pa0, pa1, pa2, pa3, (2 * t + 2) * 64);               \
    STG(sB, 0, pb0, pb1, pb2, pb3, (2 * t + 2) * 64);               \
    __builtin_amdgcn_sched_barrier(0);                              \
    CMP(1);                                                         \
    __syncthreads();                                                \
  }                                                                 \
  STG(sA, 1, pa0, pa1, pa2, pa3, ((NTILE) - 1) * 64);               \
  STG(sB, 1, pb0, pb1, pb2, pb3, ((NTILE) - 1) * 64);               \
  __builtin_amdgcn_sched_barrier(0);                                \
  CMP(0);                                                           \
  __syncthreads();                                                  \
  CMP(1);

// ---------------- gemmA<1>: G = bf16(X@W1^T + b1)  (pre-activation stash) ----
// ---------------- gemmA<2>: G = bf16(silu(G) * (X@W2^T + b2)) ----------------
// grid (32 mt, 32 ntb, NEXP): 32*128 = 4096 slot coverage (r9 bug: only 2048)
template<int MODE>
__global__ __launch_bounds__(256, 2) void gemmA_k(
    const unsigned short* __restrict__ xb, const unsigned short* __restrict__ wb,
    const float* __restrict__ bias, const int* __restrict__ rtok,
    const int* __restrict__ counts, const int* __restrict__ ebase,
    const int* __restrict__ gbase, unsigned short* __restrict__ Gx, int e0) {
  int f = blockIdx.x + gridDim.x * (blockIdx.y + gridDim.y * blockIdx.z);
  int total = gridDim.x * gridDim.y * gridDim.z;
  int cpx = total >> 3;
  int nf = (f & 7) * cpx + (f >> 3);
  int pe = gridDim.x * gridDim.y;      // 32*32 = 1024
  int ez = nf / pe;
  int r  = nf - ez * pe;
  int ntb = r >> 5;                    // [0,32)
  int mt  = r & 31;                    // [0,32) -> 4096 slots

  const int e = e0 + ez;
  const int ce = counts[e];
  if (mt * 128 >= ce) return;
  const int rb = ebase[e];
  const int gb_ = gbase[e];
  const unsigned short* wt = wb + (size_t)ez * WELEM;
  const float* be = bias + (size_t)e * HID;

  __shared__ __attribute__((aligned(16))) unsigned short sA[2][128 * 64];
  __shared__ __attribute__((aligned(16))) unsigned short sB[2][128 * 64];

  const int tid = threadIdx.x;
  const int lane = tid & 63, wid = tid >> 6;
  const int wm = wid >> 1, wn = wid & 1;
  const unsigned stg = (unsigned)(wid * 1024);

  // staging: granule g = i*256 + tid; row = i*32 + (tid>>3); pre-swizzled col
  const int grow = tid >> 3;
  const int lcol = ((tid & 7) ^ (grow & 7)) << 3;
  int sl0 = mt * 128 + grow;
  int c0 = sl0 < ce ? sl0 : ce - 1;
  int c1 = sl0 + 32 < ce ? sl0 + 32 : ce - 1;
  int c2 = sl0 + 64 < ce ? sl0 + 64 : ce - 1;
  int c3 = sl0 + 96 < ce ? sl0 + 96 : ce - 1;
  const unsigned short* pa0 = xb + (size_t)rtok[rb + c0] * DIM + lcol;
  const unsigned short* pa1 = xb + (size_t)rtok[rb + c1] * DIM + lcol;
  const unsigned short* pa2 = xb + (size_t)rtok[rb + c2] * DIM + lcol;
  const unsigned short* pa3 = xb + (size_t)rtok[rb + c3] * DIM + lcol;
  const unsigned short* pb0 = wt + (size_t)(ntb * 128 + grow) * DIM + lcol;
  const unsigned short* pb1 = pb0 + 32 * DIM;
  const unsigned short* pb2 = pb0 + 64 * DIM;
  const unsigned short* pb3 = pb0 + 96 * DIM;

  f32x4 acc[4][4] = {};
  GEMM_LOOP(16);   // K = 1024

#pragma unroll
  for (int n = 0; n < 4; ++n) {
    int col = ntb * 128 + wn * 64 + n * 16 + (lane & 15);
    float bb = be[col];
#pragma unroll
    for (int m = 0; m < 4; ++m) {
      int rbase = mt * 128 + wm * 64 + m * 16 + ((lane >> 4) << 2);
#pragma unroll
      for (int r2 = 0; r2 < 4; ++r2) {
        int slot = rbase + r2;
        if (slot < ce) {
          size_t gi = (size_t)(gb_ + slot) * HID + col;
          float h = acc[m][n][r2] + bb;
          if (MODE == 1) {
            Gx[gi] = f2bf(h);
          } else {
            float tv = bf2f(Gx[gi]);
            float sg = 1.0f / (1.0f + __expf(-tv));
            Gx[gi] = f2bf(tv * sg * h);
          }
        }
      }
    }
  }
}

// ---------------- gemm3n: out[token] += w*(G@Wp^T + bp), K=4096 ----------------
// grid (32 mt, 8 ntb, NEXP)
__global__ __launch_bounds__(256, 2) void gemm3n_k(
    const unsigned short* __restrict__ Gx, const unsigned short* __restrict__ wpb,
    const float* __restrict__ bp, const int* __restrict__ rtok,
    const float* __restrict__ rwgt, const int* __restrict__ counts,
    const int* __restrict__ ebase, const int* __restrict__ gbase,
    float* __restrict__ out, int e0) {
  int f = blockIdx.x + gridDim.x * (blockIdx.y + gridDim.y * blockIdx.z);
  int total = gridDim.x * gridDim.y * gridDim.z;
  int cpx = total >> 3;
  int nf = (f & 7) * cpx + (f >> 3);
  int pe = gridDim.x * gridDim.y;      // 32*8 = 256
  int ez = nf / pe;
  int r  = nf - ez * pe;
  int ntb = r >> 5;                    // [0,8)
  int mt  = r & 31;                    // [0,32)

  const int e = e0 + ez;
  const int ce = counts[e];
  if (mt * 128 >= ce) return;
  const int rb = ebase[e];
  const int gb_ = gbase[e];
  const unsigned short* wpt = wpb + (size_t)ez * WELEM;
  const float* bpe = bp + (size_t)e * DIM;

  __shared__ __attribute__((aligned(16))) unsigned short sA[2][128 * 64];
  __shared__ __attribute__((aligned(16))) unsigned short sB[2][128 * 64];

  const int tid = threadIdx.x;
  const int lane = tid & 63, wid = tid >> 6;
  const int wm = wid >> 1, wn = wid & 1;
  const unsigned stg = (unsigned)(wid * 1024);

  const int grow = tid >> 3;
  const int lcol = ((tid & 7) ^ (grow & 7)) << 3;
  int sl0 = mt * 128 + grow;
  int c0 = sl0 < ce ? sl0 : ce - 1;
  int c1 = sl0 + 32 < ce ? sl0 + 32 : ce - 1;
  int c2 = sl0 + 64 < ce ? sl0 + 64 : ce - 1;
  int c3 = sl0 + 96 < ce ? sl0 + 96 : ce - 1;
  const unsigned short* pa0 = Gx + (size_t)(gb_ + c0) * HID + lcol;
  const unsigned short* pa1 = Gx + (size_t)(gb_ + c1) * HID + lcol;
  const unsigned short* pa2 = Gx + (size_t)(gb_ + c2) * HID + lcol;
  const unsigned short* pa3 = Gx + (size_t)(gb_ + c3) * HID + lcol;
  const unsigned short* pb0 = wpt + (size_t)(ntb * 128 + grow) * HID + lcol;
  const unsigned short* pb1 = pb0 + (size_t)32 * HID;
  const unsigned short* pb2 = pb0 + (size_t)64 * HID;
  const unsigned short* pb3 = pb0 + (size_t)96 * HID;

  f32x4 acc[4][4] = {};
  GEMM_LOOP(64);   // K = 4096

#pragma unroll
  for (int n = 0; n < 4; ++n) {
    int col = ntb * 128 + wn * 64 + n * 16 + (lane & 15);
    float bb = bpe[col];
#pragma unroll
    for (int m = 0; m < 4; ++m) {
      int rbase = mt * 128 + wm * 64 + m * 16 + ((lane >> 4) << 2);
#pragma unroll
      for (int r2 = 0; r2 < 4; ++r2) {
        int slot = rbase + r2;
        if (slot < ce) {
          int tok = rtok[rb + slot];
          float w = rwgt[rb + slot];
          atomicAdd(out + (size_t)tok * DIM + col, w * (acc[m][n][r2] + bb));
        }
      }
    }
  }
}

// ---------------- host ----------------
extern "C" void kernel_launch(void* const* d_in, const int* in_sizes, int n_in,
                              void* d_out, int out_size, void* d_ws, size_t ws_size,
                              hipStream_t stream) {
  const float* x  = (const float*)d_in[0];
  const float* gw = (const float*)d_in[1];
  const float* gb = (const float*)d_in[2];
  const float* w1 = (const float*)d_in[3];
  const float* b1 = (const float*)d_in[4];
  const float* w2 = (const float*)d_in[5];
  const float* b2 = (const float*)d_in[6];
  const float* wp = (const float*)d_in[7];
  const float* bp = (const float*)d_in[8];
  float* out = (float*)d_out;

  char* ws = (char*)d_ws;
  const size_t BIG_NEED = 352551008ull;
  bool big = ws_size >= BIG_NEED;

  unsigned short* xb = (unsigned short*)ws;                       // 16 MB
  unsigned short *Gp, *w1a, *w2a, *wpa;
  int* tassign; float2* tprob; int* rtok; float* rwgt; int* meta;
  if (big) {
    Gp  = (unsigned short*)(ws + 16777216);      // 134.2 MB (16384 global slots)
    w1a = (unsigned short*)(ws + 150994944);     // 64 MB
    w2a = (unsigned short*)(ws + 218103808);     // 64 MB
    wpa = (unsigned short*)(ws + 285212672);     // 64 MB
    tassign = (int*)(ws + 352321536);
    tprob   = (float2*)(ws + 352354304);
    rtok    = (int*)(ws + 352419840);
    rwgt    = (float*)(ws + 352485376);
    meta    = (int*)(ws + 352550912);            // counts[8], ebase[8], zbase[8]
  } else {
    Gp  = (unsigned short*)(ws + 16777216);      // 64 MB (local slots)
    w1a = (unsigned short*)(ws + 83886080);      // 8 MB per-expert
    w2a = (unsigned short*)(ws + 92274688);
    wpa = (unsigned short*)(ws + 100663296);
    tassign = (int*)(ws + 109051904);
    tprob   = (float2*)(ws + 109084672);
    rtok    = (int*)(ws + 109150208);
    rwgt    = (float*)(ws + 109215744);
    meta    = (int*)(ws + 109281280);
  }
  int* counts = meta;
  int* ebase  = meta + 8;
  int* zbase  = meta + 16;

  hipMemsetAsync(meta, 0, 96, stream);
  hipMemsetAsync(out, 0, (size_t)(N_TOK * DIM + 1) * sizeof(float), stream);

  convert_x_k<<<4096, 256, 0, stream>>>(x, xb);
  gate2_k<<<N_TOK / 4, 256, 0, stream>>>(x, gw, gb, tassign, tprob);
  route_k<<<1, 256, 0, stream>>>(tassign, tprob, rtok, rwgt, counts, ebase);
  aux_k<<<1, 64, 0, stream>>>(counts, out);

  if (big) {
    tcvt_k<<<dim3(4096, 3, NEXP), 256, 0, stream>>>(w1, w2, wp, w1a, w2a, wpa);
    gemmA_k<1><<<dim3(32, 32, NEXP), 256, 0, stream>>>(
        xb, w1a, b1, rtok, counts, ebase, ebase, Gp, 0);
    gemmA_k<2><<<dim3(32, 32, NEXP), 256, 0, stream>>>(
        xb, w2a, b2, rtok, counts, ebase, ebase, Gp, 0);
    gemm3n_k<<<dim3(32, 8, NEXP), 256, 0, stream>>>(
        Gp, wpa, bp, rtok, rwgt, counts, ebase, ebase, out, 0);
  } else {
    for (int e = 0; e < NEXP; ++e) {
      tcvt_k<<<dim3(4096, 3, 1), 256, 0, stream>>>(
          w1 + (size_t)e * WELEM, w2 + (size_t)e * WELEM, wp + (size_t)e * WELEM,
          w1a, w2a, wpa);
      gemmA_k<1><<<dim3(32, 32, 1), 256, 0, stream>>>(
          xb, w1a, b1, rtok, counts, ebase, zbase, Gp, e);
      gemmA_k<2><<<dim3(32, 32, 1), 256, 0, stream>>>(
          xb, w2a, b2, rtok, counts, ebase, zbase, Gp, e);
      gemm3n_k<<<dim3(32, 8, 1), 256, 0, stream>>>(
          Gp, wpa, bp, rtok, rwgt, counts, ebase, zbase, out, e);
    }
  }
}

// Round 12
// 1018.902 us; speedup vs baseline: 1.2819x; 1.2157x over previous
//
#include <hip/hip_runtime.h>
#include <cstdint>
#include <cstddef>

#define N_TOK 8192
#define DIM   1024
#define NEXP  8
#define HID   4096
#define WELEM 4194304ull   // D*H elements per expert matrix

typedef __attribute__((ext_vector_type(8))) short short8v;
typedef __attribute__((ext_vector_type(4))) float f32x4;

__device__ __forceinline__ unsigned short f2bf(float f) {
  unsigned u = __builtin_bit_cast(unsigned, f);
  u += 0x7fffu + ((u >> 16) & 1u);     // RNE
  return (unsigned short)(u >> 16);
}
__device__ __forceinline__ float bf2f(unsigned short u) {
  return __builtin_bit_cast(float, (unsigned)u << 16);
}

__device__ __forceinline__ void gload16(const void* g, void* l) {
  __builtin_amdgcn_global_load_lds(
      (const __attribute__((address_space(1))) void*)g,
      (__attribute__((address_space(3))) void*)l, 16, 0, 0);
}

// ---------------- x fp32 -> bf16 ----------------
__global__ void convert_x_k(const float* __restrict__ x, unsigned short* __restrict__ xb) {
  size_t i = ((size_t)blockIdx.x * 256 + threadIdx.x) * 8;
  float4 a = *(const float4*)(x + i);
  float4 b = *(const float4*)(x + i + 4);
  short8v v;
  v[0] = (short)f2bf(a.x); v[1] = (short)f2bf(a.y); v[2] = (short)f2bf(a.z); v[3] = (short)f2bf(a.w);
  v[4] = (short)f2bf(b.x); v[5] = (short)f2bf(b.y); v[6] = (short)f2bf(b.z); v[7] = (short)f2bf(b.w);
  *(short8v*)(xb + i) = v;
}

// ---------------- gate: fp32 logits, top-2, softmax (NO atomics) ----------------
__global__ void gate2_k(const float* __restrict__ x, const float* __restrict__ gw,
                        const float* __restrict__ gb, int* __restrict__ tassign,
                        float2* __restrict__ tprob) {
  int lane = threadIdx.x & 63, wid = threadIdx.x >> 6;
  int t = blockIdx.x * 4 + wid;
  const float* xr = x + (size_t)t * DIM;
  float acc[NEXP];
#pragma unroll
  for (int e = 0; e < NEXP; ++e) acc[e] = 0.f;
#pragma unroll
  for (int j = 0; j < DIM / 256; ++j) {
    int d0 = j * 256 + lane * 4;
    float4 xv = *(const float4*)(xr + d0);
    const float* gp = gw + (size_t)d0 * NEXP;
#pragma unroll
    for (int c = 0; c < 4; ++c) {
      float xs = (c == 0) ? xv.x : (c == 1) ? xv.y : (c == 2) ? xv.z : xv.w;
      float4 g0 = *(const float4*)(gp + c * NEXP);
      float4 g1 = *(const float4*)(gp + c * NEXP + 4);
      acc[0] += xs * g0.x; acc[1] += xs * g0.y; acc[2] += xs * g0.z; acc[3] += xs * g0.w;
      acc[4] += xs * g1.x; acc[5] += xs * g1.y; acc[6] += xs * g1.z; acc[7] += xs * g1.w;
    }
  }
#pragma unroll
  for (int e = 0; e < NEXP; ++e) {
    float v = acc[e];
#pragma unroll
    for (int s = 1; s < 64; s <<= 1) v += __shfl_xor(v, s);
    acc[e] = v;
  }
  if (lane == 0) {
    float lg[NEXP];
#pragma unroll
    for (int e = 0; e < NEXP; ++e) lg[e] = acc[e] + gb[e];
    int i0 = 0;
#pragma unroll
    for (int e = 1; e < NEXP; ++e) if (lg[e] > lg[i0]) i0 = e;
    int i1 = -1;
#pragma unroll
    for (int e = 0; e < NEXP; ++e) if (e != i0 && (i1 < 0 || lg[e] > lg[i1])) i1 = e;
    float ex = expf(lg[i1] - lg[i0]);       // <= 1
    float p0 = 1.f / (1.f + ex);
    float p1 = ex * p0;
    tassign[t] = i0 | (i1 << 8);
    tprob[t] = make_float2(p0, p1);
  }
}

// ---------------- routing: single block, LDS atomics only ----------------
__global__ void route_k(const int* __restrict__ tassign, const float2* __restrict__ tprob,
                        int* __restrict__ rtok, float* __restrict__ rwgt,
                        int* __restrict__ counts, int* __restrict__ ebase) {
  __shared__ int h[NEXP];
  __shared__ int cur[NEXP];
  int tid = threadIdx.x;
  if (tid < NEXP) h[tid] = 0;
  __syncthreads();
  for (int t = tid; t < N_TOK; t += 256) {
    int a = tassign[t];
    atomicAdd(&h[a & 255], 1);
    atomicAdd(&h[(a >> 8) & 255], 1);
  }
  __syncthreads();
  if (tid == 0) {
    int b = 0;
    for (int e = 0; e < NEXP; ++e) { counts[e] = h[e]; ebase[e] = b; cur[e] = b; b += h[e]; }
  }
  __syncthreads();
  for (int t = tid; t < N_TOK; t += 256) {
    int a = tassign[t];
    float2 p = tprob[t];
    int p0 = atomicAdd(&cur[a & 255], 1);
    rtok[p0] = t; rwgt[p0] = p.x;
    int p1 = atomicAdd(&cur[(a >> 8) & 255], 1);
    rtok[p1] = t; rwgt[p1] = p.y;
  }
}

// ---------------- aux loss ----------------
__global__ void aux_k(const int* __restrict__ counts, float* __restrict__ out) {
  if (threadIdx.x == 0) {
    float tot = 0.f, c[NEXP];
    for (int e = 0; e < NEXP; ++e) { c[e] = (float)counts[e]; tot += c[e]; }
    float a = 0.f;
    for (int e = 0; e < NEXP; ++e) { float d = c[e] / tot - 0.125f; a += d * d; }
    out[(size_t)N_TOK * DIM] = a;
  }
}

// ---------------- transpose + fp32->bf16; grid (4096 tiles, 3 mats, nexp) ----------------
__global__ void tcvt_k(const float* __restrict__ w1, const float* __restrict__ w2,
                       const float* __restrict__ wp, unsigned short* __restrict__ d1,
                       unsigned short* __restrict__ d2, unsigned short* __restrict__ d3) {
  int tile = blockIdx.x, mat = blockIdx.y;
  size_t eo = (size_t)blockIdx.z * WELEM;
  const float* src; unsigned short* dst; int R, C;
  if (mat == 0)      { src = w1 + eo; dst = d1 + eo; R = DIM; C = HID; }
  else if (mat == 1) { src = w2 + eo; dst = d2 + eo; R = DIM; C = HID; }
  else               { src = wp + eo; dst = d3 + eo; R = HID; C = DIM; }
  int tilesC = C >> 5;
  int tr = (tile / tilesC) << 5;
  int tc = (tile % tilesC) << 5;
  __shared__ float tl[32][33];
  int tx = threadIdx.x & 31, ty = threadIdx.x >> 5;
#pragma unroll
  for (int i = 0; i < 32; i += 8) tl[ty + i][tx] = src[(size_t)(tr + ty + i) * C + tc + tx];
  __syncthreads();
#pragma unroll
  for (int i = 0; i < 32; i += 8) dst[(size_t)(tc + ty + i) * R + tr + tx] = f2bf(tl[tx][ty + i]);
}

// ================= 128x128 m97-structure GEMM core =================
// 256 threads, 4 waves (2M x 2N), wave tile 64x64, BK=64,
// SINGLE-buffered sA/sB = 32 KB LDS -> 4-5 blocks/CU; latency hiding comes
// from inter-block wave overlap (m97/m114), not explicit pipelining.
// Per K-step: sync (LDS reuse safe) -> STAGE -> sync (vmcnt drain) -> CMP.
#define STG(SD, P0, P1, P2, P3, K0)                                 \
  gload16(P0 + (K0), (char*)SD + stg);                              \
  gload16(P1 + (K0), (char*)SD + stg + 4096);                       \
  gload16(P2 + (K0), (char*)SD + stg + 8192);                       \
  gload16(P3 + (K0), (char*)SD + stg + 12288);

#define CMP()                                                       \
  {                                                                 \
    _Pragma("unroll")                                               \
    for (int s = 0; s < 2; ++s) {                                   \
      short8v af[4], bf[4];                                         \
      _Pragma("unroll")                                             \
      for (int m = 0; m < 4; ++m) {                                 \
        int row = wm * 64 + m * 16 + (lane & 15);                   \
        int p = (s * 4 + (lane >> 4)) ^ (row & 7);                  \
        af[m] = *(const short8v*)((const char*)sA + row * 128 + p * 16); \
      }                                                             \
      _Pragma("unroll")                                             \
      for (int n = 0; n < 4; ++n) {                                 \
        int row = wn * 64 + n * 16 + (lane & 15);                   \
        int p = (s * 4 + (lane >> 4)) ^ (row & 7);                  \
        bf[n] = *(const short8v*)((const char*)sB + row * 128 + p * 16); \
      }                                                             \
      _Pragma("unroll")                                             \
      for (int m = 0; m < 4; ++m)                                   \
        _Pragma("unroll")                                           \
        for (int n = 0; n < 4; ++n)                                 \
          acc[m][n] = __builtin_amdgcn_mfma_f32_16x16x32_bf16(af[m], bf[n], acc[m][n], 0, 0, 0); \
    }                                                               \
  }

#define GEMM_LOOP(NTILE)                                            \
  _Pragma("unroll 1")                                               \
  for (int t = 0; t < (NTILE); ++t) {                               \
    __syncthreads();                                                \
    STG(sA, pa0, pa1, pa2, pa3, t * 64);                            \
    STG(sB, pb0, pb1, pb2, pb3, t * 64);                            \
    __syncthreads();                                                \
    CMP();                                                          \
  }

// ---------------- gemmA<1>: G = bf16(X@W1^T + b1)  (pre-activation stash) ----
// ---------------- gemmA<2>: G = bf16(silu(G) * (X@W2^T + b2)) ----------------
// grid (32 mt, 32 ntb, NEXP): 4096-slot coverage per expert
template<int MODE>
__global__ __launch_bounds__(256, 4) void gemmA_k(
    const unsigned short* __restrict__ xb, const unsigned short* __restrict__ wb,
    const float* __restrict__ bias, const int* __restrict__ rtok,
    const int* __restrict__ counts, const int* __restrict__ ebase,
    const int* __restrict__ gbase, unsigned short* __restrict__ Gx, int e0) {
  int f = blockIdx.x + gridDim.x * (blockIdx.y + gridDim.y * blockIdx.z);
  int total = gridDim.x * gridDim.y * gridDim.z;
  int cpx = total >> 3;
  int nf = (f & 7) * cpx + (f >> 3);
  int pe = gridDim.x * gridDim.y;      // 32*32 = 1024
  int ez = nf / pe;
  int r  = nf - ez * pe;
  int ntb = r >> 5;                    // [0,32)
  int mt  = r & 31;                    // [0,32)

  const int e = e0 + ez;
  const int ce = counts[e];
  if (mt * 128 >= ce) return;
  const int rb = ebase[e];
  const int gb_ = gbase[e];
  const unsigned short* wt = wb + (size_t)ez * WELEM;
  const float* be = bias + (size_t)e * HID;

  __shared__ __attribute__((aligned(16))) unsigned short sA[128 * 64];
  __shared__ __attribute__((aligned(16))) unsigned short sB[128 * 64];

  const int tid = threadIdx.x;
  const int lane = tid & 63, wid = tid >> 6;
  const int wm = wid >> 1, wn = wid & 1;
  const unsigned stg = (unsigned)(wid * 1024);

  // staging: granule g = i*256 + tid; row = i*32 + (tid>>3); pre-swizzled col
  const int grow = tid >> 3;
  const int lcol = ((tid & 7) ^ (grow & 7)) << 3;
  int sl0 = mt * 128 + grow;
  int c0 = sl0 < ce ? sl0 : ce - 1;
  int c1 = sl0 + 32 < ce ? sl0 + 32 : ce - 1;
  int c2 = sl0 + 64 < ce ? sl0 + 64 : ce - 1;
  int c3 = sl0 + 96 < ce ? sl0 + 96 : ce - 1;
  const unsigned short* pa0 = xb + (size_t)rtok[rb + c0] * DIM + lcol;
  const unsigned short* pa1 = xb + (size_t)rtok[rb + c1] * DIM + lcol;
  const unsigned short* pa2 = xb + (size_t)rtok[rb + c2] * DIM + lcol;
  const unsigned short* pa3 = xb + (size_t)rtok[rb + c3] * DIM + lcol;
  const unsigned short* pb0 = wt + (size_t)(ntb * 128 + grow) * DIM + lcol;
  const unsigned short* pb1 = pb0 + 32 * DIM;
  const unsigned short* pb2 = pb0 + 64 * DIM;
  const unsigned short* pb3 = pb0 + 96 * DIM;

  f32x4 acc[4][4] = {};
  GEMM_LOOP(16);   // K = 1024

#pragma unroll
  for (int n = 0; n < 4; ++n) {
    int col = ntb * 128 + wn * 64 + n * 16 + (lane & 15);
    float bb = be[col];
#pragma unroll
    for (int m = 0; m < 4; ++m) {
      int rbase = mt * 128 + wm * 64 + m * 16 + ((lane >> 4) << 2);
#pragma unroll
      for (int r2 = 0; r2 < 4; ++r2) {
        int slot = rbase + r2;
        if (slot < ce) {
          size_t gi = (size_t)(gb_ + slot) * HID + col;
          float h = acc[m][n][r2] + bb;
          if (MODE == 1) {
            Gx[gi] = f2bf(h);
          } else {
            float tv = bf2f(Gx[gi]);
            float sg = 1.0f / (1.0f + __expf(-tv));
            Gx[gi] = f2bf(tv * sg * h);
          }
        }
      }
    }
  }
}

// ---------------- gemm3n: out[token] += w*(G@Wp^T + bp), K=4096 ----------------
// grid (32 mt, 8 ntb, NEXP)
__global__ __launch_bounds__(256, 4) void gemm3n_k(
    const unsigned short* __restrict__ Gx, const unsigned short* __restrict__ wpb,
    const float* __restrict__ bp, const int* __restrict__ rtok,
    const float* __restrict__ rwgt, const int* __restrict__ counts,
    const int* __restrict__ ebase, const int* __restrict__ gbase,
    float* __restrict__ out, int e0) {
  int f = blockIdx.x + gridDim.x * (blockIdx.y + gridDim.y * blockIdx.z);
  int total = gridDim.x * gridDim.y * gridDim.z;
  int cpx = total >> 3;
  int nf = (f & 7) * cpx + (f >> 3);
  int pe = gridDim.x * gridDim.y;      // 32*8 = 256
  int ez = nf / pe;
  int r  = nf - ez * pe;
  int ntb = r >> 5;                    // [0,8)
  int mt  = r & 31;                    // [0,32)

  const int e = e0 + ez;
  const int ce = counts[e];
  if (mt * 128 >= ce) return;
  const int rb = ebase[e];
  const int gb_ = gbase[e];
  const unsigned short* wpt = wpb + (size_t)ez * WELEM;
  const float* bpe = bp + (size_t)e * DIM;

  __shared__ __attribute__((aligned(16))) unsigned short sA[128 * 64];
  __shared__ __attribute__((aligned(16))) unsigned short sB[128 * 64];

  const int tid = threadIdx.x;
  const int lane = tid & 63, wid = tid >> 6;
  const int wm = wid >> 1, wn = wid & 1;
  const unsigned stg = (unsigned)(wid * 1024);

  const int grow = tid >> 3;
  const int lcol = ((tid & 7) ^ (grow & 7)) << 3;
  int sl0 = mt * 128 + grow;
  int c0 = sl0 < ce ? sl0 : ce - 1;
  int c1 = sl0 + 32 < ce ? sl0 + 32 : ce - 1;
  int c2 = sl0 + 64 < ce ? sl0 + 64 : ce - 1;
  int c3 = sl0 + 96 < ce ? sl0 + 96 : ce - 1;
  const unsigned short* pa0 = Gx + (size_t)(gb_ + c0) * HID + lcol;
  const unsigned short* pa1 = Gx + (size_t)(gb_ + c1) * HID + lcol;
  const unsigned short* pa2 = Gx + (size_t)(gb_ + c2) * HID + lcol;
  const unsigned short* pa3 = Gx + (size_t)(gb_ + c3) * HID + lcol;
  const unsigned short* pb0 = wpt + (size_t)(ntb * 128 + grow) * HID + lcol;
  const unsigned short* pb1 = pb0 + (size_t)32 * HID;
  const unsigned short* pb2 = pb0 + (size_t)64 * HID;
  const unsigned short* pb3 = pb0 + (size_t)96 * HID;

  f32x4 acc[4][4] = {};
  GEMM_LOOP(64);   // K = 4096

#pragma unroll
  for (int n = 0; n < 4; ++n) {
    int col = ntb * 128 + wn * 64 + n * 16 + (lane & 15);
    float bb = bpe[col];
#pragma unroll
    for (int m = 0; m < 4; ++m) {
      int rbase = mt * 128 + wm * 64 + m * 16 + ((lane >> 4) << 2);
#pragma unroll
      for (int r2 = 0; r2 < 4; ++r2) {
        int slot = rbase + r2;
        if (slot < ce) {
          int tok = rtok[rb + slot];
          float w = rwgt[rb + slot];
          atomicAdd(out + (size_t)tok * DIM + col, w * (acc[m][n][r2] + bb));
        }
      }
    }
  }
}

// ---------------- host ----------------
extern "C" void kernel_launch(void* const* d_in, const int* in_sizes, int n_in,
                              void* d_out, int out_size, void* d_ws, size_t ws_size,
                              hipStream_t stream) {
  const float* x  = (const float*)d_in[0];
  const float* gw = (const float*)d_in[1];
  const float* gb = (const float*)d_in[2];
  const float* w1 = (const float*)d_in[3];
  const float* b1 = (const float*)d_in[4];
  const float* w2 = (const float*)d_in[5];
  const float* b2 = (const float*)d_in[6];
  const float* wp = (const float*)d_in[7];
  const float* bp = (const float*)d_in[8];
  float* out = (float*)d_out;

  char* ws = (char*)d_ws;
  const size_t BIG_NEED = 352551008ull;
  bool big = ws_size >= BIG_NEED;

  unsigned short* xb = (unsigned short*)ws;                       // 16 MB
  unsigned short *Gp, *w1a, *w2a, *wpa;
  int* tassign; float2* tprob; int* rtok; float* rwgt; int* meta;
  if (big) {
    Gp  = (unsigned short*)(ws + 16777216);      // 134.2 MB (16384 global slots)
    w1a = (unsigned short*)(ws + 150994944);     // 64 MB
    w2a = (unsigned short*)(ws + 218103808);     // 64 MB
    wpa = (unsigned short*)(ws + 285212672);     // 64 MB
    tassign = (int*)(ws + 352321536);
    tprob   = (float2*)(ws + 352354304);
    rtok    = (int*)(ws + 352419840);
    rwgt    = (float*)(ws + 352485376);
    meta    = (int*)(ws + 352550912);            // counts[8], ebase[8], zbase[8]
  } else {
    Gp  = (unsigned short*)(ws + 16777216);      // 64 MB (local slots)
    w1a = (unsigned short*)(ws + 83886080);      // 8 MB per-expert
    w2a = (unsigned short*)(ws + 92274688);
    wpa = (unsigned short*)(ws + 100663296);
    tassign = (int*)(ws + 109051904);
    tprob   = (float2*)(ws + 109084672);
    rtok    = (int*)(ws + 109150208);
    rwgt    = (float*)(ws + 109215744);
    meta    = (int*)(ws + 109281280);
  }
  int* counts = meta;
  int* ebase  = meta + 8;
  int* zbase  = meta + 16;

  hipMemsetAsync(meta, 0, 96, stream);
  hipMemsetAsync(out, 0, (size_t)(N_TOK * DIM + 1) * sizeof(float), stream);

  convert_x_k<<<4096, 256, 0, stream>>>(x, xb);
  gate2_k<<<N_TOK / 4, 256, 0, stream>>>(x, gw, gb, tassign, tprob);
  route_k<<<1, 256, 0, stream>>>(tassign, tprob, rtok, rwgt, counts, ebase);
  aux_k<<<1, 64, 0, stream>>>(counts, out);

  if (big) {
    tcvt_k<<<dim3(4096, 3, NEXP), 256, 0, stream>>>(w1, w2, wp, w1a, w2a, wpa);
    gemmA_k<1><<<dim3(32, 32, NEXP), 256, 0, stream>>>(
        xb, w1a, b1, rtok, counts, ebase, ebase, Gp, 0);
    gemmA_k<2><<<dim3(32, 32, NEXP), 256, 0, stream>>>(
        xb, w2a, b2, rtok, counts, ebase, ebase, Gp, 0);
    gemm3n_k<<<dim3(32, 8, NEXP), 256, 0, stream>>>(
        Gp, wpa, bp, rtok, rwgt, counts, ebase, ebase, out, 0);
  } else {
    for (int e = 0; e < NEXP; ++e) {
      tcvt_k<<<dim3(4096, 3, 1), 256, 0, stream>>>(
          w1 + (size_t)e * WELEM, w2 + (size_t)e * WELEM, wp + (size_t)e * WELEM,
          w1a, w2a, wpa);
      gemmA_k<1><<<dim3(32, 32, 1), 256, 0, stream>>>(
          xb, w1a, b1, rtok, counts, ebase, zbase, Gp, e);
      gemmA_k<2><<<dim3(32, 32, 1), 256, 0, stream>>>(
          xb, w2a, b2, rtok, counts, ebase, zbase, Gp, e);
      gemm3n_k<<<dim3(32, 8, 1), 256, 0, stream>>>(
          Gp, wpa, bp, rtok, rwgt, counts, ebase, zbase, out, e);
    }
  }
}

// Round 13
// 817.415 us; speedup vs baseline: 1.5979x; 1.2465x over previous
//
#include <hip/hip_runtime.h>
#include <cstdint>
#include <cstddef>

#define N_TOK 8192
#define DIM   1024
#define NEXP  8
#define HID   4096
#define WELEM 4194304ull   // D*H elements per expert matrix

typedef __attribute__((ext_vector_type(8))) short short8v;
typedef __attribute__((ext_vector_type(4))) float f32x4;

__device__ __forceinline__ unsigned short f2bf(float f) {
  unsigned u = __builtin_bit_cast(unsigned, f);
  u += 0x7fffu + ((u >> 16) & 1u);     // RNE
  return (unsigned short)(u >> 16);
}

__device__ __forceinline__ void gload16(const void* g, void* l) {
  __builtin_amdgcn_global_load_lds(
      (const __attribute__((address_space(1))) void*)g,
      (__attribute__((address_space(3))) void*)l, 16, 0, 0);
}

// ---------------- x fp32 -> bf16 ----------------
__global__ void convert_x_k(const float* __restrict__ x, unsigned short* __restrict__ xb) {
  size_t i = ((size_t)blockIdx.x * 256 + threadIdx.x) * 8;
  float4 a = *(const float4*)(x + i);
  float4 b = *(const float4*)(x + i + 4);
  short8v v;
  v[0] = (short)f2bf(a.x); v[1] = (short)f2bf(a.y); v[2] = (short)f2bf(a.z); v[3] = (short)f2bf(a.w);
  v[4] = (short)f2bf(b.x); v[5] = (short)f2bf(b.y); v[6] = (short)f2bf(b.z); v[7] = (short)f2bf(b.w);
  *(short8v*)(xb + i) = v;
}

// ---------------- gate: fp32 logits, top-2, softmax (NO atomics) ----------------
__global__ void gate2_k(const float* __restrict__ x, const float* __restrict__ gw,
                        const float* __restrict__ gb, int* __restrict__ tassign,
                        float2* __restrict__ tprob) {
  int lane = threadIdx.x & 63, wid = threadIdx.x >> 6;
  int t = blockIdx.x * 4 + wid;
  const float* xr = x + (size_t)t * DIM;
  float acc[NEXP];
#pragma unroll
  for (int e = 0; e < NEXP; ++e) acc[e] = 0.f;
#pragma unroll
  for (int j = 0; j < DIM / 256; ++j) {
    int d0 = j * 256 + lane * 4;
    float4 xv = *(const float4*)(xr + d0);
    const float* gp = gw + (size_t)d0 * NEXP;
#pragma unroll
    for (int c = 0; c < 4; ++c) {
      float xs = (c == 0) ? xv.x : (c == 1) ? xv.y : (c == 2) ? xv.z : xv.w;
      float4 g0 = *(const float4*)(gp + c * NEXP);
      float4 g1 = *(const float4*)(gp + c * NEXP + 4);
      acc[0] += xs * g0.x; acc[1] += xs * g0.y; acc[2] += xs * g0.z; acc[3] += xs * g0.w;
      acc[4] += xs * g1.x; acc[5] += xs * g1.y; acc[6] += xs * g1.z; acc[7] += xs * g1.w;
    }
  }
#pragma unroll
  for (int e = 0; e < NEXP; ++e) {
    float v = acc[e];
#pragma unroll
    for (int s = 1; s < 64; s <<= 1) v += __shfl_xor(v, s);
    acc[e] = v;
  }
  if (lane == 0) {
    float lg[NEXP];
#pragma unroll
    for (int e = 0; e < NEXP; ++e) lg[e] = acc[e] + gb[e];
    int i0 = 0;
#pragma unroll
    for (int e = 1; e < NEXP; ++e) if (lg[e] > lg[i0]) i0 = e;
    int i1 = -1;
#pragma unroll
    for (int e = 0; e < NEXP; ++e) if (e != i0 && (i1 < 0 || lg[e] > lg[i1])) i1 = e;
    float ex = expf(lg[i1] - lg[i0]);       // <= 1
    float p0 = 1.f / (1.f + ex);
    float p1 = ex * p0;
    tassign[t] = i0 | (i1 << 8);
    tprob[t] = make_float2(p0, p1);
  }
}

// ---------------- routing: single block, LDS atomics only ----------------
__global__ void route_k(const int* __restrict__ tassign, const float2* __restrict__ tprob,
                        int* __restrict__ rtok, float* __restrict__ rwgt,
                        int* __restrict__ counts, int* __restrict__ ebase) {
  __shared__ int h[NEXP];
  __shared__ int cur[NEXP];
  int tid = threadIdx.x;
  if (tid < NEXP) h[tid] = 0;
  __syncthreads();
  for (int t = tid; t < N_TOK; t += 256) {
    int a = tassign[t];
    atomicAdd(&h[a & 255], 1);
    atomicAdd(&h[(a >> 8) & 255], 1);
  }
  __syncthreads();
  if (tid == 0) {
    int b = 0;
    for (int e = 0; e < NEXP; ++e) { counts[e] = h[e]; ebase[e] = b; cur[e] = b; b += h[e]; }
  }
  __syncthreads();
  for (int t = tid; t < N_TOK; t += 256) {
    int a = tassign[t];
    float2 p = tprob[t];
    int p0 = atomicAdd(&cur[a & 255], 1);
    rtok[p0] = t; rwgt[p0] = p.x;
    int p1 = atomicAdd(&cur[(a >> 8) & 255], 1);
    rtok[p1] = t; rwgt[p1] = p.y;
  }
}

// ---------------- aux loss ----------------
__global__ void aux_k(const int* __restrict__ counts, float* __restrict__ out) {
  if (threadIdx.x == 0) {
    float tot = 0.f, c[NEXP];
    for (int e = 0; e < NEXP; ++e) { c[e] = (float)counts[e]; tot += c[e]; }
    float a = 0.f;
    for (int e = 0; e < NEXP; ++e) { float d = c[e] / tot - 0.125f; a += d * d; }
    out[(size_t)N_TOK * DIM] = a;
  }
}

// ---------------- transpose + fp32->bf16; grid (4096 tiles, 3 mats, nexp) ----------------
__global__ void tcvt_k(const float* __restrict__ w1, const float* __restrict__ w2,
                       const float* __restrict__ wp, unsigned short* __restrict__ d1,
                       unsigned short* __restrict__ d2, unsigned short* __restrict__ d3) {
  int tile = blockIdx.x, mat = blockIdx.y;
  size_t eo = (size_t)blockIdx.z * WELEM;
  const float* src; unsigned short* dst; int R, C;
  if (mat == 0)      { src = w1 + eo; dst = d1 + eo; R = DIM; C = HID; }
  else if (mat == 1) { src = w2 + eo; dst = d2 + eo; R = DIM; C = HID; }
  else               { src = wp + eo; dst = d3 + eo; R = HID; C = DIM; }
  int tilesC = C >> 5;
  int tr = (tile / tilesC) << 5;
  int tc = (tile % tilesC) << 5;
  __shared__ float tl[32][33];
  int tx = threadIdx.x & 31, ty = threadIdx.x >> 5;
#pragma unroll
  for (int i = 0; i < 32; i += 8) tl[ty + i][tx] = src[(size_t)(tr + ty + i) * C + tc + tx];
  __syncthreads();
#pragma unroll
  for (int i = 0; i < 32; i += 8) dst[(size_t)(tc + ty + i) * R + tr + tx] = f2bf(tl[tx][ty + i]);
}

// ================= gemm12m: fused dual-B, m97 structure =================
// BM=128 slots, BN=64 (both h1 and h2 for those 64 cols), BK=64.
// 256 thr / 4 waves (2M x 2N), wave tile 64x32 per B-matrix.
// acc1[4][2]+acc2[4][2] = 64 AGPR; ~80 VGPR -> ~145 total -> 3 waves/SIMD.
// LDS: sA 16KB + sB1 8KB + sB2 8KB = 32KB single-buffered -> reg-capped 3 blk/CU.
// Per K-step: sync -> STAGE(A,B1,B2) -> sync -> CMP.  (m97 form)
template<int DUMMY>
__global__ __launch_bounds__(256, 3) void gemm12m_k(
    const unsigned short* __restrict__ xb,
    const unsigned short* __restrict__ w1b, const unsigned short* __restrict__ w2b,
    const float* __restrict__ b1, const float* __restrict__ b2,
    const int* __restrict__ rtok, const int* __restrict__ counts,
    const int* __restrict__ ebase, const int* __restrict__ gbase,
    unsigned short* __restrict__ Gx, int e0) {
  int f = blockIdx.x + gridDim.x * (blockIdx.y + gridDim.y * blockIdx.z);
  int total = gridDim.x * gridDim.y * gridDim.z;
  int cpx = total >> 3;
  int nf = (f & 7) * cpx + (f >> 3);
  int pe = gridDim.x * gridDim.y;      // 32*64 = 2048
  int ez = nf / pe;
  int r  = nf - ez * pe;
  int ntb = r >> 5;                    // [0,64)  (64-wide H tiles)
  int mt  = r & 31;                    // [0,32)

  const int e = e0 + ez;
  const int ce = counts[e];
  if (mt * 128 >= ce) return;
  const int rb = ebase[e];
  const int gb_ = gbase[e];
  const unsigned short* w1t = w1b + (size_t)ez * WELEM;
  const unsigned short* w2t = w2b + (size_t)ez * WELEM;
  const float* b1e = b1 + (size_t)e * HID;
  const float* b2e = b2 + (size_t)e * HID;

  __shared__ __attribute__((aligned(16))) unsigned short sA[128 * 64];
  __shared__ __attribute__((aligned(16))) unsigned short sB1[64 * 64];
  __shared__ __attribute__((aligned(16))) unsigned short sB2[64 * 64];

  const int tid = threadIdx.x;
  const int lane = tid & 63, wid = tid >> 6;
  const int wm = wid >> 1, wn = wid & 1;
  const unsigned stg = (unsigned)(wid * 1024);

  // staging: granule g = c*256 + tid; row = c*32 + (tid>>3); XOR-pre-swizzled col
  const int grow = tid >> 3;
  const int lcol = ((tid & 7) ^ (grow & 7)) << 3;
  int sl0 = mt * 128 + grow;
  int c0 = sl0 < ce ? sl0 : ce - 1;
  int c1 = sl0 + 32 < ce ? sl0 + 32 : ce - 1;
  int c2 = sl0 + 64 < ce ? sl0 + 64 : ce - 1;
  int c3 = sl0 + 96 < ce ? sl0 + 96 : ce - 1;
  const unsigned short* pa0 = xb + (size_t)rtok[rb + c0] * DIM + lcol;
  const unsigned short* pa1 = xb + (size_t)rtok[rb + c1] * DIM + lcol;
  const unsigned short* pa2 = xb + (size_t)rtok[rb + c2] * DIM + lcol;
  const unsigned short* pa3 = xb + (size_t)rtok[rb + c3] * DIM + lcol;
  const unsigned short* pq1 = w1t + (size_t)(ntb * 64 + grow) * DIM + lcol;  // rows [0,32)
  const unsigned short* pq2 = w2t + (size_t)(ntb * 64 + grow) * DIM + lcol;

  f32x4 acc1[4][2] = {};
  f32x4 acc2[4][2] = {};

#pragma unroll 1
  for (int t = 0; t < 16; ++t) {
    const int k0 = t * 64;
    __syncthreads();
    gload16(pa0 + k0, (char*)sA + stg);
    gload16(pa1 + k0, (char*)sA + stg + 4096);
    gload16(pa2 + k0, (char*)sA + stg + 8192);
    gload16(pa3 + k0, (char*)sA + stg + 12288);
    gload16(pq1 + k0, (char*)sB1 + stg);
    gload16(pq1 + k0 + 32 * DIM, (char*)sB1 + stg + 4096);
    gload16(pq2 + k0, (char*)sB2 + stg);
    gload16(pq2 + k0 + 32 * DIM, (char*)sB2 + stg + 4096);
    __syncthreads();
#pragma unroll
    for (int s = 0; s < 2; ++s) {
      short8v af[4], bf1[2], bf2[2];
#pragma unroll
      for (int m = 0; m < 4; ++m) {
        int row = wm * 64 + m * 16 + (lane & 15);
        int p = (s * 4 + (lane >> 4)) ^ (row & 7);
        af[m] = *(const short8v*)((const char*)sA + row * 128 + p * 16);
      }
#pragma unroll
      for (int n = 0; n < 2; ++n) {
        int row = wn * 32 + n * 16 + (lane & 15);
        int p = (s * 4 + (lane >> 4)) ^ (row & 7);
        bf1[n] = *(const short8v*)((const char*)sB1 + row * 128 + p * 16);
        bf2[n] = *(const short8v*)((const char*)sB2 + row * 128 + p * 16);
      }
#pragma unroll
      for (int m = 0; m < 4; ++m)
#pragma unroll
        for (int n = 0; n < 2; ++n) {
          acc1[m][n] = __builtin_amdgcn_mfma_f32_16x16x32_bf16(af[m], bf1[n], acc1[m][n], 0, 0, 0);
          acc2[m][n] = __builtin_amdgcn_mfma_f32_16x16x32_bf16(af[m], bf2[n], acc2[m][n], 0, 0, 0);
        }
    }
  }

#pragma unroll
  for (int n = 0; n < 2; ++n) {
    int col = ntb * 64 + wn * 32 + n * 16 + (lane & 15);
    float bb1 = b1e[col], bb2 = b2e[col];
#pragma unroll
    for (int m = 0; m < 4; ++m) {
      int rbase = mt * 128 + wm * 64 + m * 16 + ((lane >> 4) << 2);
#pragma unroll
      for (int r2 = 0; r2 < 4; ++r2) {
        int slot = rbase + r2;
        if (slot < ce) {
          float h1 = acc1[m][n][r2] + bb1;
          float h2 = acc2[m][n][r2] + bb2;
          float sg = 1.0f / (1.0f + __expf(-h1));
          Gx[(size_t)(gb_ + slot) * HID + col] = f2bf(h1 * sg * h2);
        }
      }
    }
  }
}

// ================= 128x128 m97-structure GEMM core (gemm3n) =================
#define STG(SD, P0, P1, P2, P3, K0)                                 \
  gload16(P0 + (K0), (char*)SD + stg);                              \
  gload16(P1 + (K0), (char*)SD + stg + 4096);                       \
  gload16(P2 + (K0), (char*)SD + stg + 8192);                       \
  gload16(P3 + (K0), (char*)SD + stg + 12288);

#define CMP()                                                       \
  {                                                                 \
    _Pragma("unroll")                                               \
    for (int s = 0; s < 2; ++s) {                                   \
      short8v af[4], bf[4];                                         \
      _Pragma("unroll")                                             \
      for (int m = 0; m < 4; ++m) {                                 \
        int row = wm * 64 + m * 16 + (lane & 15);                   \
        int p = (s * 4 + (lane >> 4)) ^ (row & 7);                  \
        af[m] = *(const short8v*)((const char*)sA + row * 128 + p * 16); \
      }                                                             \
      _Pragma("unroll")                                             \
      for (int n = 0; n < 4; ++n) {                                 \
        int row = wn * 64 + n * 16 + (lane & 15);                   \
        int p = (s * 4 + (lane >> 4)) ^ (row & 7);                  \
        bf[n] = *(const short8v*)((const char*)sB + row * 128 + p * 16); \
      }                                                             \
      _Pragma("unroll")                                             \
      for (int m = 0; m < 4; ++m)                                   \
        _Pragma("unroll")                                           \
        for (int n = 0; n < 4; ++n)                                 \
          acc[m][n] = __builtin_amdgcn_mfma_f32_16x16x32_bf16(af[m], bf[n], acc[m][n], 0, 0, 0); \
    }                                                               \
  }

#define GEMM_LOOP(NTILE)                                            \
  _Pragma("unroll 1")                                               \
  for (int t = 0; t < (NTILE); ++t) {                               \
    __syncthreads();                                                \
    STG(sA, pa0, pa1, pa2, pa3, t * 64);                            \
    STG(sB, pb0, pb1, pb2, pb3, t * 64);                            \
    __syncthreads();                                                \
    CMP();                                                          \
  }

// ---------------- gemm3n: out[token] += w*(G@Wp^T + bp), K=4096 ----------------
// grid (32 mt, 8 ntb, NEXP)
__global__ __launch_bounds__(256, 4) void gemm3n_k(
    const unsigned short* __restrict__ Gx, const unsigned short* __restrict__ wpb,
    const float* __restrict__ bp, const int* __restrict__ rtok,
    const float* __restrict__ rwgt, const int* __restrict__ counts,
    const int* __restrict__ ebase, const int* __restrict__ gbase,
    float* __restrict__ out, int e0) {
  int f = blockIdx.x + gridDim.x * (blockIdx.y + gridDim.y * blockIdx.z);
  int total = gridDim.x * gridDim.y * gridDim.z;
  int cpx = total >> 3;
  int nf = (f & 7) * cpx + (f >> 3);
  int pe = gridDim.x * gridDim.y;      // 32*8 = 256
  int ez = nf / pe;
  int r  = nf - ez * pe;
  int ntb = r >> 5;                    // [0,8)
  int mt  = r & 31;                    // [0,32)

  const int e = e0 + ez;
  const int ce = counts[e];
  if (mt * 128 >= ce) return;
  const int rb = ebase[e];
  const int gb_ = gbase[e];
  const unsigned short* wpt = wpb + (size_t)ez * WELEM;
  const float* bpe = bp + (size_t)e * DIM;

  __shared__ __attribute__((aligned(16))) unsigned short sA[128 * 64];
  __shared__ __attribute__((aligned(16))) unsigned short sB[128 * 64];

  const int tid = threadIdx.x;
  const int lane = tid & 63, wid = tid >> 6;
  const int wm = wid >> 1, wn = wid & 1;
  const unsigned stg = (unsigned)(wid * 1024);

  const int grow = tid >> 3;
  const int lcol = ((tid & 7) ^ (grow & 7)) << 3;
  int sl0 = mt * 128 + grow;
  int c0 = sl0 < ce ? sl0 : ce - 1;
  int c1 = sl0 + 32 < ce ? sl0 + 32 : ce - 1;
  int c2 = sl0 + 64 < ce ? sl0 + 64 : ce - 1;
  int c3 = sl0 + 96 < ce ? sl0 + 96 : ce - 1;
  const unsigned short* pa0 = Gx + (size_t)(gb_ + c0) * HID + lcol;
  const unsigned short* pa1 = Gx + (size_t)(gb_ + c1) * HID + lcol;
  const unsigned short* pa2 = Gx + (size_t)(gb_ + c2) * HID + lcol;
  const unsigned short* pa3 = Gx + (size_t)(gb_ + c3) * HID + lcol;
  const unsigned short* pb0 = wpt + (size_t)(ntb * 128 + grow) * HID + lcol;
  const unsigned short* pb1 = pb0 + (size_t)32 * HID;
  const unsigned short* pb2 = pb0 + (size_t)64 * HID;
  const unsigned short* pb3 = pb0 + (size_t)96 * HID;

  f32x4 acc[4][4] = {};
  GEMM_LOOP(64);   // K = 4096

#pragma unroll
  for (int n = 0; n < 4; ++n) {
    int col = ntb * 128 + wn * 64 + n * 16 + (lane & 15);
    float bb = bpe[col];
#pragma unroll
    for (int m = 0; m < 4; ++m) {
      int rbase = mt * 128 + wm * 64 + m * 16 + ((lane >> 4) << 2);
#pragma unroll
      for (int r2 = 0; r2 < 4; ++r2) {
        int slot = rbase + r2;
        if (slot < ce) {
          int tok = rtok[rb + slot];
          float w = rwgt[rb + slot];
          atomicAdd(out + (size_t)tok * DIM + col, w * (acc[m][n][r2] + bb));
        }
      }
    }
  }
}

// ---------------- host ----------------
extern "C" void kernel_launch(void* const* d_in, const int* in_sizes, int n_in,
                              void* d_out, int out_size, void* d_ws, size_t ws_size,
                              hipStream_t stream) {
  const float* x  = (const float*)d_in[0];
  const float* gw = (const float*)d_in[1];
  const float* gb = (const float*)d_in[2];
  const float* w1 = (const float*)d_in[3];
  const float* b1 = (const float*)d_in[4];
  const float* w2 = (const float*)d_in[5];
  const float* b2 = (const float*)d_in[6];
  const float* wp = (const float*)d_in[7];
  const float* bp = (const float*)d_in[8];
  float* out = (float*)d_out;

  char* ws = (char*)d_ws;
  const size_t BIG_NEED = 352551008ull;
  bool big = ws_size >= BIG_NEED;

  unsigned short* xb = (unsigned short*)ws;                       // 16 MB
  unsigned short *Gp, *w1a, *w2a, *wpa;
  int* tassign; float2* tprob; int* rtok; float* rwgt; int* meta;
  if (big) {
    Gp  = (unsigned short*)(ws + 16777216);      // 134.2 MB (16384 global slots)
    w1a = (unsigned short*)(ws + 150994944);     // 64 MB
    w2a = (unsigned short*)(ws + 218103808);     // 64 MB
    wpa = (unsigned short*)(ws + 285212672);     // 64 MB
    tassign = (int*)(ws + 352321536);
    tprob   = (float2*)(ws + 352354304);
    rtok    = (int*)(ws + 352419840);
    rwgt    = (float*)(ws + 352485376);
    meta    = (int*)(ws + 352550912);            // counts[8], ebase[8], zbase[8]
  } else {
    Gp  = (unsigned short*)(ws + 16777216);      // 64 MB (local slots)
    w1a = (unsigned short*)(ws + 83886080);      // 8 MB per-expert
    w2a = (unsigned short*)(ws + 92274688);
    wpa = (unsigned short*)(ws + 100663296);
    tassign = (int*)(ws + 109051904);
    tprob   = (float2*)(ws + 109084672);
    rtok    = (int*)(ws + 109150208);
    rwgt    = (float*)(ws + 109215744);
    meta    = (int*)(ws + 109281280);
  }
  int* counts = meta;
  int* ebase  = meta + 8;
  int* zbase  = meta + 16;

  hipMemsetAsync(meta, 0, 96, stream);
  hipMemsetAsync(out, 0, (size_t)(N_TOK * DIM + 1) * sizeof(float), stream);

  convert_x_k<<<4096, 256, 0, stream>>>(x, xb);
  gate2_k<<<N_TOK / 4, 256, 0, stream>>>(x, gw, gb, tassign, tprob);
  route_k<<<1, 256, 0, stream>>>(tassign, tprob, rtok, rwgt, counts, ebase);
  aux_k<<<1, 64, 0, stream>>>(counts, out);

  if (big) {
    tcvt_k<<<dim3(4096, 3, NEXP), 256, 0, stream>>>(w1, w2, wp, w1a, w2a, wpa);
    gemm12m_k<0><<<dim3(32, 64, NEXP), 256, 0, stream>>>(
        xb, w1a, w2a, b1, b2, rtok, counts, ebase, ebase, Gp, 0);
    gemm3n_k<<<dim3(32, 8, NEXP), 256, 0, stream>>>(
        Gp, wpa, bp, rtok, rwgt, counts, ebase, ebase, out, 0);
  } else {
    for (int e = 0; e < NEXP; ++e) {
      tcvt_k<<<dim3(4096, 3, 1), 256, 0, stream>>>(
          w1 + (size_t)e * WELEM, w2 + (size_t)e * WELEM, wp + (size_t)e * WELEM,
          w1a, w2a, wpa);
      gemm12m_k<0><<<dim3(32, 64, 1), 256, 0, stream>>>(
          xb, w1a, w2a, b1, b2, rtok, counts, ebase, zbase, Gp, e);
      gemm3n_k<<<dim3(32, 8, 1), 256, 0, stream>>>(
          Gp, wpa, bp, rtok, rwgt, counts, ebase, zbase, out, e);
    }
  }
}